// Round 6
// baseline (1037.911 us; speedup 1.0000x reference)
//
#include <hip/hip_runtime.h>

// ---------------------------------------------------------------------------
// GCN forward, reassociated: per layer h = relu( (A_hat h) W + b ).
// R5: FUSED layer kernel — pull-aggregate (CSR, no atomics) gathers directly
// into the LDS A-tile, then the 128x128 GEMM runs on it. Removes the P
// round-trip (102 MB/layer) and hides GEMM VALU under gather memory time.
// CSR stores only srcs (vals = dinv[src] gathered from L2-resident dinv —
// halves fill_edges' scattered writes, which R5 showed at 12x amplification).
// R4 lesson kept: pooling is two-stage and atomic-free (sorted batch would
// serialize atomics on 512 addresses).
// NOTE: harness delivers integer inputs as int32 (edge_index/batch: int*).
// ---------------------------------------------------------------------------

constexpr int D = 128;
constexpr int NGRAPH = 512;
constexpr int AP = 132;   // A-tile pitch (floats): 132 mod 32 = 4 -> reads 2-way max (free)

__global__ __launch_bounds__(256) void zero_i4(int4* __restrict__ p, int n4) {
    int i = blockIdx.x * 256 + threadIdx.x;
    if (i < n4) p[i] = make_int4(0, 0, 0, 0);
}

// degi[c] += 1 per incoming edge (self-loop +1 added in make_dinv)
__global__ __launch_bounds__(256) void count_deg(const int* __restrict__ col,
                                                 int E, int* __restrict__ degi) {
    int e = blockIdx.x * 256 + threadIdx.x;
    if (e < E) atomicAdd(&degi[col[e]], 1);
}

__global__ __launch_bounds__(256) void make_dinv(const int* __restrict__ degi,
                                                 float* __restrict__ dinv, int N) {
    int n = blockIdx.x * 256 + threadIdx.x;
    if (n < N) dinv[n] = rsqrtf((float)degi[n] + 1.0f);
}

// ---- 3-phase exclusive prefix sum over degi[N] -> rowptr[N+1] --------------
__global__ __launch_bounds__(256) void scan1(const int* __restrict__ deg, int N,
                                             int* __restrict__ bsum) {
    __shared__ int s[256];
    int t = threadIdx.x, base = blockIdx.x * 1024 + t * 4;
    int v = 0;
#pragma unroll
    for (int i = 0; i < 4; ++i) { int idx = base + i; if (idx < N) v += deg[idx]; }
    s[t] = v; __syncthreads();
    for (int off = 128; off > 0; off >>= 1) {
        if (t < off) s[t] += s[t + off];
        __syncthreads();
    }
    if (t == 0) bsum[blockIdx.x] = s[0];
}

__global__ __launch_bounds__(256) void scan2(int* __restrict__ bsum, int NB) {
    __shared__ int s[256];
    int t = threadIdx.x;
    int v = (t < NB) ? bsum[t] : 0;
    s[t] = v; __syncthreads();
    for (int off = 1; off < 256; off <<= 1) {
        int x = (t >= off) ? s[t - off] : 0;
        __syncthreads();
        s[t] += x;
        __syncthreads();
    }
    if (t < NB) bsum[t] = s[t] - v;   // exclusive
}

__global__ __launch_bounds__(256) void scan3(const int* __restrict__ deg,
                                             const int* __restrict__ bsumEx,
                                             int N, int E, int* __restrict__ rowptr) {
    __shared__ int s[256];
    int t = threadIdx.x, base = blockIdx.x * 1024 + t * 4;
    int v[4], sum = 0;
#pragma unroll
    for (int i = 0; i < 4; ++i) { int idx = base + i; v[i] = (idx < N) ? deg[idx] : 0; sum += v[i]; }
    s[t] = sum; __syncthreads();
    for (int off = 1; off < 256; off <<= 1) {
        int x = (t >= off) ? s[t - off] : 0;
        __syncthreads();
        s[t] += x;
        __syncthreads();
    }
    int run = bsumEx[blockIdx.x] + s[t] - sum;
#pragma unroll
    for (int i = 0; i < 4; ++i) {
        int idx = base + i;
        if (idx < N) rowptr[idx] = run;
        run += v[i];
    }
    if (blockIdx.x == 0 && t == 0) rowptr[N] = E;
}

// slot-fill: srcs grouped by target node (order within a node arbitrary)
__global__ __launch_bounds__(256) void fill_edges(const int* __restrict__ er,
                                                  const int* __restrict__ ec, int E,
                                                  const int* __restrict__ rowptr,
                                                  int* __restrict__ cursor,
                                                  int* __restrict__ srcs) {
    int e = blockIdx.x * 256 + threadIdx.x;
    if (e >= E) return;
    int r = er[e], c = ec[e];
    int pos = rowptr[c] + atomicAdd(&cursor[c], 1);
    srcs[pos] = r;
}

// ---- FUSED layer: P[tile] = relu( Ahat_tile(H) @ W + bias ) ---------------
// Phase 1: each half-wave gathers 8 nodes' normalized aggregate rows into the
// LDS A-tile (64 x 128, pitch AP). Phase 2: 128x128 GEMM, W staged in 32-row
// chunks, thread computes 4 nodes x 8 cols. ~50 KB LDS -> 3 blocks/CU.
__global__ __launch_bounds__(256) void gcn_layer(const int* __restrict__ rowptr,
                                                 const int* __restrict__ srcs,
                                                 const float* __restrict__ dinv,
                                                 const float* __restrict__ H,
                                                 const float* __restrict__ W,
                                                 const float* __restrict__ bias,
                                                 float* __restrict__ P, int N) {
    __shared__ __align__(16) float sA[64 * AP];     // 33.8 KB
    __shared__ __align__(16) float sW[32 * 128];    // 16 KB

    const int tid = threadIdx.x;
    const int n0 = blockIdx.x * 64;
    const float4* H4 = (const float4*)H;

    // ---- phase 1: gather 8 nodes per half-wave ----
    {
        const int hw = tid >> 5;          // 0..7
        const int lane = tid & 31;
#pragma unroll
        for (int i = 0; i < 8; ++i) {
            const int nl = hw * 8 + i;
            const int node = n0 + nl;
            float4 acc = make_float4(0.f, 0.f, 0.f, 0.f);
            if (node < N) {
                int j = rowptr[node], je = rowptr[node + 1];
                float sn = dinv[node];
                float4 hs = H4[(size_t)node * 32 + lane];
                acc = make_float4(sn * hs.x, sn * hs.y, sn * hs.z, sn * hs.w);
                for (; j + 7 < je; j += 8) {
                    int r[8]; float s[8]; float4 h[8];
#pragma unroll
                    for (int t = 0; t < 8; ++t) r[t] = srcs[j + t];
#pragma unroll
                    for (int t = 0; t < 8; ++t) s[t] = dinv[r[t]];
#pragma unroll
                    for (int t = 0; t < 8; ++t) h[t] = H4[(size_t)r[t] * 32 + lane];
#pragma unroll
                    for (int t = 0; t < 8; ++t) {
                        acc.x += s[t] * h[t].x; acc.y += s[t] * h[t].y;
                        acc.z += s[t] * h[t].z; acc.w += s[t] * h[t].w;
                    }
                }
                for (; j < je; ++j) {
                    int r0 = srcs[j];
                    float s0 = dinv[r0];
                    float4 h0 = H4[(size_t)r0 * 32 + lane];
                    acc.x += s0 * h0.x; acc.y += s0 * h0.y;
                    acc.z += s0 * h0.z; acc.w += s0 * h0.w;
                }
                acc.x *= sn; acc.y *= sn; acc.z *= sn; acc.w *= sn;
            }
            ((float4*)(sA + nl * AP))[lane] = acc;
        }
    }

    // ---- phase 2: GEMM (A-tile in LDS) ----
    const int tx = tid & 15;   // cols 8*tx .. 8*tx+7
    const int ty = tid >> 4;   // nodes 4*ty .. 4*ty+3
    float acc[4][8];
#pragma unroll
    for (int i = 0; i < 4; ++i)
#pragma unroll
        for (int j = 0; j < 8; ++j) acc[i][j] = 0.0f;

    const float4* W4 = (const float4*)W;
    for (int kc = 0; kc < 4; ++kc) {
#pragma unroll
        for (int i = 0; i < 4; ++i) {
            int f = tid + i * 256;
            int r = f >> 5, c4 = f & 31;
            ((float4*)sW)[r * 32 + c4] = W4[(kc * 32 + r) * 32 + c4];
        }
        __syncthreads();   // covers phase-1 sA writes on kc==0, sW staging always

#pragma unroll 8
        for (int k = 0; k < 32; ++k) {
            const int kg = kc * 32 + k;
            const float a_[4] = { sA[(4 * ty + 0) * AP + kg], sA[(4 * ty + 1) * AP + kg],
                                  sA[(4 * ty + 2) * AP + kg], sA[(4 * ty + 3) * AP + kg] };
            const float4 w0 = *(const float4*)(sW + k * 128 + 8 * tx);
            const float4 w1 = *(const float4*)(sW + k * 128 + 8 * tx + 4);
            const float w_[8] = {w0.x, w0.y, w0.z, w0.w, w1.x, w1.y, w1.z, w1.w};
#pragma unroll
            for (int i = 0; i < 4; ++i)
#pragma unroll
                for (int j = 0; j < 8; ++j) acc[i][j] += a_[i] * w_[j];
        }
        __syncthreads();
    }

    const float4 b0 = ((const float4*)bias)[2 * tx];
    const float4 b1 = ((const float4*)bias)[2 * tx + 1];
#pragma unroll
    for (int i = 0; i < 4; ++i) {
        int node = n0 + 4 * ty + i;
        if (node < N) {
            float4 o0, o1;
            o0.x = fmaxf(acc[i][0] + b0.x, 0.f);
            o0.y = fmaxf(acc[i][1] + b0.y, 0.f);
            o0.z = fmaxf(acc[i][2] + b0.z, 0.f);
            o0.w = fmaxf(acc[i][3] + b0.w, 0.f);
            o1.x = fmaxf(acc[i][4] + b1.x, 0.f);
            o1.y = fmaxf(acc[i][5] + b1.y, 0.f);
            o1.z = fmaxf(acc[i][6] + b1.z, 0.f);
            o1.w = fmaxf(acc[i][7] + b1.w, 0.f);
            ((float4*)P)[(size_t)node * 32 + 2 * tx] = o0;
            ((float4*)P)[(size_t)node * 32 + 2 * tx + 1] = o1;
        }
    }
}

// dots[n] = H[n][:] . Wl  — one wave per node, no atomics
__global__ __launch_bounds__(256) void node_dot(const float* __restrict__ H,
                                                const float* __restrict__ Wl,
                                                float* __restrict__ dots, int N) {
    long long gt = (long long)blockIdx.x * 256 + threadIdx.x;
    int n = (int)(gt >> 6);
    int lane = (int)(gt & 63);
    if (n >= N) return;
    float v = H[(size_t)n * 128 + lane] * Wl[lane] +
              H[(size_t)n * 128 + 64 + lane] * Wl[64 + lane];
#pragma unroll
    for (int off = 32; off > 0; off >>= 1) v += __shfl_down(v, off, 64);
    if (lane == 0) dots[n] = v;
}

// one block per graph: binary-search node range in sorted batch, mean, +bl
__global__ __launch_bounds__(256) void pool_graphs(const float* __restrict__ dots,
                                                   const int* __restrict__ batch, int N,
                                                   const float* __restrict__ bl,
                                                   float* __restrict__ out) {
    __shared__ int bounds[2];
    __shared__ float red[4];
    const int g = blockIdx.x;
    const int t = threadIdx.x;
    if (t < 2) {
        int key = g + t;             // lower_bound(batch, key)
        int lo = 0, hi = N;
        while (lo < hi) {
            int mid = (lo + hi) >> 1;
            if (batch[mid] < key) lo = mid + 1; else hi = mid;
        }
        bounds[t] = lo;
    }
    __syncthreads();
    const int lo = bounds[0], hi = bounds[1];
    float s = 0.f;
    for (int i = lo + t; i < hi; i += 256) s += dots[i];
#pragma unroll
    for (int off = 32; off > 0; off >>= 1) s += __shfl_down(s, off, 64);
    if ((t & 63) == 0) red[t >> 6] = s;
    __syncthreads();
    if (t == 0) {
        float tot = red[0] + red[1] + red[2] + red[3];
        int cnt = hi - lo;
        out[g] = tot / (float)(cnt > 0 ? cnt : 1) + bl[0];
    }
}

extern "C" void kernel_launch(void* const* d_in, const int* in_sizes, int n_in,
                              void* d_out, int out_size, void* d_ws, size_t ws_size,
                              hipStream_t stream) {
    const float* x     = (const float*)d_in[0];
    const int*   eidx  = (const int*)d_in[1];    // int32 (harness converts int64)
    const int*   batch = (const int*)d_in[2];
    const float* Ws    = (const float*)d_in[3];
    const float* bs    = (const float*)d_in[4];
    const float* Wl    = (const float*)d_in[5];
    const float* bl    = (const float*)d_in[6];
    (void)n_in; (void)out_size;

    const int N = in_sizes[0] / D;
    const int E = in_sizes[1] / 2;
    const int* er = eidx;       // sources
    const int* ec = eidx + E;   // targets

    // ---- workspace carve ----
    const size_t bufBytes = (size_t)N * D * sizeof(float);   // 51.2 MB
    const int Npad = (N + 63) & ~63;
    auto al = [](size_t v) { return (v + 255) & ~(size_t)255; };
    char* base = (char*)d_ws;
    size_t off = 0;

    float* wsA = (float*)base;               off = al(bufBytes);
    // zero-block: degi, cursor (contiguous -> one zero kernel)
    int*   degi   = (int*)(base + off);
    int*   cursor = degi + Npad;
    const int zeroInts = 2 * Npad;
    off = al(off + (size_t)zeroInts * sizeof(int));
    float* dinv   = (float*)(base + off);    off = al(off + (size_t)Npad * sizeof(float));
    float* dots   = (float*)(base + off);    off = al(off + (size_t)Npad * sizeof(float));
    int*   rowptr = (int*)(base + off);      off = al(off + (size_t)(Npad + 64) * sizeof(int));
    int*   bsum   = (int*)(base + off);      off = al(off + 256 * sizeof(int));
    int*   srcs   = (int*)(base + off);      off = al(off + (size_t)E * sizeof(int));

    const bool twoBuf = ws_size >= off + bufBytes;
    float* wsB = twoBuf ? (float*)(base + off) : (float*)d_in[0];
    float* bufs[2] = { wsA, wsB };

    // ---- CSR build (once; reused by all 4 layers) ----
    zero_i4<<<(zeroInts / 4 + 255) / 256, 256, 0, stream>>>((int4*)degi, zeroInts / 4);
    count_deg<<<(E + 255) / 256, 256, 0, stream>>>(ec, E, degi);
    make_dinv<<<(N + 255) / 256, 256, 0, stream>>>(degi, dinv, N);
    const int NB = (N + 1023) / 1024;
    scan1<<<NB, 256, 0, stream>>>(degi, N, bsum);
    scan2<<<1, 256, 0, stream>>>(bsum, NB);
    scan3<<<NB, 256, 0, stream>>>(degi, bsum, N, E, rowptr);
    fill_edges<<<(E + 255) / 256, 256, 0, stream>>>(er, ec, E, rowptr, cursor, srcs);

    // ---- 4 fused layers ----
    for (int i = 0; i < 4; ++i) {
        float* P = bufs[i & 1];
        const float* H = (i == 0) ? x : bufs[(i - 1) & 1];
        gcn_layer<<<(N + 63) / 64, 256, 0, stream>>>(rowptr, srcs, dinv, H,
                                                     Ws + (size_t)i * D * D,
                                                     bs + (size_t)i * D, P, N);
    }

    // ---- mean pool + linear head (final features in bufs[1]) ----
    long long tot = (long long)N * 64;
    node_dot<<<(int)((tot + 255) / 256), 256, 0, stream>>>(bufs[1], Wl, dots, N);
    pool_graphs<<<NGRAPH, 256, 0, stream>>>(dots, batch, N, bl, (float*)d_out);
}

// Round 7
// 976.825 us; speedup vs baseline: 1.0625x; 1.0625x over previous
//
#include <hip/hip_runtime.h>

// ---------------------------------------------------------------------------
// GCN forward, reassociated: per layer h = relu( (A_hat h) W + b ).
// R6 lesson: the CSR gather is LATENCY-bound -> maximize independent blocks
// and loads-in-flight; do NOT fuse with the GEMM (fusion dropped occupancy
// 71%->28% and regressed). Split kernels:
//   pull_agg: half-wave per node, 8-edge load batches, full norm folded:
//             P[n] = dinv[n]*(sum dinv[src]*H[src] + dinv[n]*H[n])
//   gemm_agg: in-place 128x128-tile GEMM (+bias+relu), k-major LDS A-tile.
// CSR (srcs only, grouped by target) built once, reused by all 4 layers.
// Pooling is two-stage and atomic-free (sorted batch serializes atomics).
// NOTE: harness delivers integer inputs as int32 (edge_index/batch: int*).
// ---------------------------------------------------------------------------

constexpr int D = 128;
constexpr int NGRAPH = 512;
constexpr int SA_PITCH = 136;  // k-major A-tile pitch: 136 mod 32 = 8 -> conflict-free reads

__global__ __launch_bounds__(256) void zero_i4(int4* __restrict__ p, int n4) {
    int i = blockIdx.x * 256 + threadIdx.x;
    if (i < n4) p[i] = make_int4(0, 0, 0, 0);
}

// degi[c] += 1 per incoming edge (self-loop +1 added in make_dinv)
__global__ __launch_bounds__(256) void count_deg(const int* __restrict__ col,
                                                 int E, int* __restrict__ degi) {
    int e = blockIdx.x * 256 + threadIdx.x;
    if (e < E) atomicAdd(&degi[col[e]], 1);
}

__global__ __launch_bounds__(256) void make_dinv(const int* __restrict__ degi,
                                                 float* __restrict__ dinv, int N) {
    int n = blockIdx.x * 256 + threadIdx.x;
    if (n < N) dinv[n] = rsqrtf((float)degi[n] + 1.0f);
}

// ---- 3-phase exclusive prefix sum over degi[N] -> rowptr[N+1] --------------
__global__ __launch_bounds__(256) void scan1(const int* __restrict__ deg, int N,
                                             int* __restrict__ bsum) {
    __shared__ int s[256];
    int t = threadIdx.x, base = blockIdx.x * 1024 + t * 4;
    int v = 0;
#pragma unroll
    for (int i = 0; i < 4; ++i) { int idx = base + i; if (idx < N) v += deg[idx]; }
    s[t] = v; __syncthreads();
    for (int off = 128; off > 0; off >>= 1) {
        if (t < off) s[t] += s[t + off];
        __syncthreads();
    }
    if (t == 0) bsum[blockIdx.x] = s[0];
}

__global__ __launch_bounds__(256) void scan2(int* __restrict__ bsum, int NB) {
    __shared__ int s[256];
    int t = threadIdx.x;
    int v = (t < NB) ? bsum[t] : 0;
    s[t] = v; __syncthreads();
    for (int off = 1; off < 256; off <<= 1) {
        int x = (t >= off) ? s[t - off] : 0;
        __syncthreads();
        s[t] += x;
        __syncthreads();
    }
    if (t < NB) bsum[t] = s[t] - v;   // exclusive
}

__global__ __launch_bounds__(256) void scan3(const int* __restrict__ deg,
                                             const int* __restrict__ bsumEx,
                                             int N, int E, int* __restrict__ rowptr) {
    __shared__ int s[256];
    int t = threadIdx.x, base = blockIdx.x * 1024 + t * 4;
    int v[4], sum = 0;
#pragma unroll
    for (int i = 0; i < 4; ++i) { int idx = base + i; v[i] = (idx < N) ? deg[idx] : 0; sum += v[i]; }
    s[t] = sum; __syncthreads();
    for (int off = 1; off < 256; off <<= 1) {
        int x = (t >= off) ? s[t - off] : 0;
        __syncthreads();
        s[t] += x;
        __syncthreads();
    }
    int run = bsumEx[blockIdx.x] + s[t] - sum;
#pragma unroll
    for (int i = 0; i < 4; ++i) {
        int idx = base + i;
        if (idx < N) rowptr[idx] = run;
        run += v[i];
    }
    if (blockIdx.x == 0 && t == 0) rowptr[N] = E;
}

// slot-fill: srcs grouped by target node (order within a node arbitrary)
__global__ __launch_bounds__(256) void fill_edges(const int* __restrict__ er,
                                                  const int* __restrict__ ec, int E,
                                                  const int* __restrict__ rowptr,
                                                  int* __restrict__ cursor,
                                                  int* __restrict__ srcs) {
    int e = blockIdx.x * 256 + threadIdx.x;
    if (e >= E) return;
    int r = er[e], c = ec[e];
    int pos = rowptr[c] + atomicAdd(&cursor[c], 1);
    srcs[pos] = r;
}

// P[n][:] = dinv[n] * ( sum_j dinv[srcs[j]]*H[srcs[j]][:] + dinv[n]*H[n][:] )
// Half-wave (32 lanes x float4) per node; 8-edge batches, loads-first for MLP.
__global__ __launch_bounds__(256) void pull_agg(const int* __restrict__ rowptr,
                                                const int* __restrict__ srcs,
                                                const float* __restrict__ dinv,
                                                const float* __restrict__ H,
                                                float* __restrict__ P, int N) {
    int node = blockIdx.x * 8 + (threadIdx.x >> 5);
    int lane = threadIdx.x & 31;
    if (node >= N) return;
    int j = rowptr[node], end = rowptr[node + 1];
    const float4* H4 = (const float4*)H;
    float sn = dinv[node];
    float4 hs = H4[(size_t)node * 32 + lane];
    float4 acc = make_float4(sn * hs.x, sn * hs.y, sn * hs.z, sn * hs.w);
    for (; j + 8 <= end; j += 8) {
        int r[8]; float s[8]; float4 h[8];
#pragma unroll
        for (int t = 0; t < 8; ++t) r[t] = srcs[j + t];
#pragma unroll
        for (int t = 0; t < 8; ++t) s[t] = dinv[r[t]];
#pragma unroll
        for (int t = 0; t < 8; ++t) h[t] = H4[(size_t)r[t] * 32 + lane];
#pragma unroll
        for (int t = 0; t < 8; ++t) {
            acc.x += s[t] * h[t].x; acc.y += s[t] * h[t].y;
            acc.z += s[t] * h[t].z; acc.w += s[t] * h[t].w;
        }
    }
    for (; j < end; ++j) {
        int r0 = srcs[j];
        float s0 = dinv[r0];
        float4 h0 = H4[(size_t)r0 * 32 + lane];
        acc.x += s0 * h0.x; acc.y += s0 * h0.y;
        acc.z += s0 * h0.z; acc.w += s0 * h0.w;
    }
    acc.x *= sn; acc.y *= sn; acc.z *= sn; acc.w *= sn;
    ((float4*)P)[(size_t)node * 32 + lane] = acc;
}

// In-place: P[n][:] = relu( P[n][:] @ W + bias ).  128 nodes x 128 cols/block,
// thread = 8 nodes x 8 cols (64 acc). sA k-major (conflict-free inner reads).
__global__ __launch_bounds__(256) void gemm_agg(float* __restrict__ P,
                                                const float* __restrict__ W,
                                                const float* __restrict__ bias, int N) {
    __shared__ __align__(16) float sW[32 * 128];        // 16.4 KB
    __shared__ __align__(16) float sA[32 * SA_PITCH];   // 17.4 KB

    const int tid = threadIdx.x;
    const int tx = tid & 15;   // cols 8*tx .. 8*tx+7
    const int ty = tid >> 4;   // nodes 8*ty .. 8*ty+7 (ty in 0..15)
    const int n0 = blockIdx.x * 128;

    float acc[8][8];
#pragma unroll
    for (int i = 0; i < 8; ++i)
#pragma unroll
        for (int j = 0; j < 8; ++j) acc[i][j] = 0.0f;

    const float4* P4 = (const float4*)P;
    const float4* W4 = (const float4*)W;

    for (int kc = 0; kc < 4; ++kc) {
        // stage W rows [kc*32, kc*32+32) x 128 : 1024 float4, 4/thread
#pragma unroll
        for (int i = 0; i < 4; ++i) {
            int f = tid + i * 256;
            int r = f >> 5, c4 = f & 31;
            ((float4*)sW)[r * 32 + c4] = W4[(kc * 32 + r) * 32 + c4];
        }
        // stage A: 128 nodes x 32 k, transposed to k-major: 1024 float4, 4/thread
#pragma unroll
        for (int i = 0; i < 4; ++i) {
            int f = tid + i * 256;
            int n = f >> 3, c4 = f & 7;
            int node = n0 + n;
            float4 a = (node < N) ? P4[(size_t)node * 32 + kc * 8 + c4]
                                  : make_float4(0.f, 0.f, 0.f, 0.f);
            int kl = c4 * 4;
            sA[(kl + 0) * SA_PITCH + n] = a.x;
            sA[(kl + 1) * SA_PITCH + n] = a.y;
            sA[(kl + 2) * SA_PITCH + n] = a.z;
            sA[(kl + 3) * SA_PITCH + n] = a.w;
        }
        __syncthreads();

#pragma unroll 4
        for (int k = 0; k < 32; ++k) {
            float a_[8];
#pragma unroll
            for (int i = 0; i < 8; ++i) a_[i] = sA[k * SA_PITCH + 8 * ty + i];
            const float4 w0 = *(const float4*)(sW + k * 128 + 8 * tx);
            const float4 w1 = *(const float4*)(sW + k * 128 + 8 * tx + 4);
            const float w_[8] = {w0.x, w0.y, w0.z, w0.w, w1.x, w1.y, w1.z, w1.w};
#pragma unroll
            for (int i = 0; i < 8; ++i)
#pragma unroll
                for (int j = 0; j < 8; ++j) acc[i][j] += a_[i] * w_[j];
        }
        __syncthreads();
    }

    const float4 b0 = ((const float4*)bias)[2 * tx];
    const float4 b1 = ((const float4*)bias)[2 * tx + 1];
#pragma unroll
    for (int i = 0; i < 8; ++i) {
        int node = n0 + 8 * ty + i;
        if (node < N) {
            float4 o0, o1;
            o0.x = fmaxf(acc[i][0] + b0.x, 0.f);
            o0.y = fmaxf(acc[i][1] + b0.y, 0.f);
            o0.z = fmaxf(acc[i][2] + b0.z, 0.f);
            o0.w = fmaxf(acc[i][3] + b0.w, 0.f);
            o1.x = fmaxf(acc[i][4] + b1.x, 0.f);
            o1.y = fmaxf(acc[i][5] + b1.y, 0.f);
            o1.z = fmaxf(acc[i][6] + b1.z, 0.f);
            o1.w = fmaxf(acc[i][7] + b1.w, 0.f);
            ((float4*)P)[(size_t)node * 32 + 2 * tx] = o0;
            ((float4*)P)[(size_t)node * 32 + 2 * tx + 1] = o1;
        }
    }
}

// dots[n] = H[n][:] . Wl  — one wave per node, no atomics
__global__ __launch_bounds__(256) void node_dot(const float* __restrict__ H,
                                                const float* __restrict__ Wl,
                                                float* __restrict__ dots, int N) {
    long long gt = (long long)blockIdx.x * 256 + threadIdx.x;
    int n = (int)(gt >> 6);
    int lane = (int)(gt & 63);
    if (n >= N) return;
    float v = H[(size_t)n * 128 + lane] * Wl[lane] +
              H[(size_t)n * 128 + 64 + lane] * Wl[64 + lane];
#pragma unroll
    for (int off = 32; off > 0; off >>= 1) v += __shfl_down(v, off, 64);
    if (lane == 0) dots[n] = v;
}

// one block per graph: binary-search node range in sorted batch, mean, +bl
__global__ __launch_bounds__(256) void pool_graphs(const float* __restrict__ dots,
                                                   const int* __restrict__ batch, int N,
                                                   const float* __restrict__ bl,
                                                   float* __restrict__ out) {
    __shared__ int bounds[2];
    __shared__ float red[4];
    const int g = blockIdx.x;
    const int t = threadIdx.x;
    if (t < 2) {
        int key = g + t;             // lower_bound(batch, key)
        int lo = 0, hi = N;
        while (lo < hi) {
            int mid = (lo + hi) >> 1;
            if (batch[mid] < key) lo = mid + 1; else hi = mid;
        }
        bounds[t] = lo;
    }
    __syncthreads();
    const int lo = bounds[0], hi = bounds[1];
    float s = 0.f;
    for (int i = lo + t; i < hi; i += 256) s += dots[i];
#pragma unroll
    for (int off = 32; off > 0; off >>= 1) s += __shfl_down(s, off, 64);
    if ((t & 63) == 0) red[t >> 6] = s;
    __syncthreads();
    if (t == 0) {
        float tot = red[0] + red[1] + red[2] + red[3];
        int cnt = hi - lo;
        out[g] = tot / (float)(cnt > 0 ? cnt : 1) + bl[0];
    }
}

extern "C" void kernel_launch(void* const* d_in, const int* in_sizes, int n_in,
                              void* d_out, int out_size, void* d_ws, size_t ws_size,
                              hipStream_t stream) {
    const float* x     = (const float*)d_in[0];
    const int*   eidx  = (const int*)d_in[1];    // int32 (harness converts int64)
    const int*   batch = (const int*)d_in[2];
    const float* Ws    = (const float*)d_in[3];
    const float* bs    = (const float*)d_in[4];
    const float* Wl    = (const float*)d_in[5];
    const float* bl    = (const float*)d_in[6];
    (void)n_in; (void)out_size;

    const int N = in_sizes[0] / D;
    const int E = in_sizes[1] / 2;
    const int* er = eidx;       // sources
    const int* ec = eidx + E;   // targets

    // ---- workspace carve ----
    const size_t bufBytes = (size_t)N * D * sizeof(float);   // 51.2 MB
    const int Npad = (N + 63) & ~63;
    auto al = [](size_t v) { return (v + 255) & ~(size_t)255; };
    char* base = (char*)d_ws;
    size_t off = 0;

    float* wsA = (float*)base;               off = al(bufBytes);
    // zero-block: degi, cursor (contiguous -> one zero kernel)
    int*   degi   = (int*)(base + off);
    int*   cursor = degi + Npad;
    const int zeroInts = 2 * Npad;
    off = al(off + (size_t)zeroInts * sizeof(int));
    float* dinv   = (float*)(base + off);    off = al(off + (size_t)Npad * sizeof(float));
    float* dots   = (float*)(base + off);    off = al(off + (size_t)Npad * sizeof(float));
    int*   rowptr = (int*)(base + off);      off = al(off + (size_t)(Npad + 64) * sizeof(int));
    int*   bsum   = (int*)(base + off);      off = al(off + 256 * sizeof(int));
    int*   srcs   = (int*)(base + off);      off = al(off + (size_t)E * sizeof(int));

    const bool twoBuf = ws_size >= off + bufBytes;
    float* wsB = twoBuf ? (float*)(base + off) : (float*)d_in[0];
    float* bufs[2] = { wsA, wsB };

    // ---- CSR build (once; reused by all 4 layers) ----
    zero_i4<<<(zeroInts / 4 + 255) / 256, 256, 0, stream>>>((int4*)degi, zeroInts / 4);
    count_deg<<<(E + 255) / 256, 256, 0, stream>>>(ec, E, degi);
    make_dinv<<<(N + 255) / 256, 256, 0, stream>>>(degi, dinv, N);
    const int NB = (N + 1023) / 1024;
    scan1<<<NB, 256, 0, stream>>>(degi, N, bsum);
    scan2<<<1, 256, 0, stream>>>(bsum, NB);
    scan3<<<NB, 256, 0, stream>>>(degi, bsum, N, E, rowptr);
    fill_edges<<<(E + 255) / 256, 256, 0, stream>>>(er, ec, E, rowptr, cursor, srcs);

    // ---- 4 layers: pull-aggregate (no atomics) -> in-place GEMM ----
    for (int i = 0; i < 4; ++i) {
        float* P = bufs[i & 1];
        const float* H = (i == 0) ? x : bufs[(i - 1) & 1];
        pull_agg<<<(N + 7) / 8, 256, 0, stream>>>(rowptr, srcs, dinv, H, P, N);
        gemm_agg<<<(N + 127) / 128, 256, 0, stream>>>(P, Ws + (size_t)i * D * D,
                                                      bs + (size_t)i * D, N);
    }

    // ---- mean pool + linear head (final features in bufs[1]) ----
    long long tot = (long long)N * 64;
    node_dot<<<(int)((tot + 255) / 256), 256, 0, stream>>>(bufs[1], Wl, dots, N);
    pool_graphs<<<NGRAPH, 256, 0, stream>>>(dots, batch, N, bl, (float*)d_out);
}

// Round 8
// 792.071 us; speedup vs baseline: 1.3104x; 1.2333x over previous
//
#include <hip/hip_runtime.h>

// ---------------------------------------------------------------------------
// GCN forward, reassociated: per layer h = relu( (A_hat h) W + b ).
// R7 lesson: pull_agg is THROUGHPUT-bound at ~3.8 TB/s of L3->L2 line traffic
// (FETCH = 8 XCDs x |H|, structural for random edges; extra MLP gave +2%).
// => R8: halve the bytes. H is stored BF16 for the gather (footprint 51.2 ->
// 25.6 MB), accumulation in fp32. Error budget: max|ref| ~ 0.024, threshold
// 4.8e-4 ~ 2% relative; bf16 rounding ~0.2%/element with fp32 accumulate ->
// ~4x margin. Pipeline per layer: pull(Hb bf16 -> P fp32) ; gemm(P fp32 ->
// Hb' bf16, +bias+relu). No in-place hazard anymore.
// Kept: CSR (srcs only) built once; atomic-free two-stage pooling.
// NOTE: harness delivers integer inputs as int32 (edge_index/batch: int*).
// ---------------------------------------------------------------------------

constexpr int D = 128;
constexpr int NGRAPH = 512;
constexpr int SA_PITCH = 136;  // k-major A-tile pitch: 136 mod 32 = 8 -> conflict-free reads

__device__ __forceinline__ float bf2f(unsigned short b) {
    return __uint_as_float(((unsigned int)b) << 16);
}
__device__ __forceinline__ unsigned short f2bf(float f) {   // round-to-nearest-even
    unsigned int u = __float_as_uint(f);
    u += 0x7FFFu + ((u >> 16) & 1u);
    return (unsigned short)(u >> 16);
}

__global__ __launch_bounds__(256) void zero_i4(int4* __restrict__ p, int n4) {
    int i = blockIdx.x * 256 + threadIdx.x;
    if (i < n4) p[i] = make_int4(0, 0, 0, 0);
}

// x fp32 -> bf16 feature buffer
__global__ __launch_bounds__(256) void cast_bf16(const float4* __restrict__ x4,
                                                 ushort4* __restrict__ hb, int n4) {
    int i = blockIdx.x * 256 + threadIdx.x;
    if (i >= n4) return;
    float4 v = x4[i];
    ushort4 o;
    o.x = f2bf(v.x); o.y = f2bf(v.y); o.z = f2bf(v.z); o.w = f2bf(v.w);
    hb[i] = o;
}

// degi[c] += 1 per incoming edge (self-loop +1 added in make_dinv)
__global__ __launch_bounds__(256) void count_deg(const int* __restrict__ col,
                                                 int E, int* __restrict__ degi) {
    int e = blockIdx.x * 256 + threadIdx.x;
    if (e < E) atomicAdd(&degi[col[e]], 1);
}

__global__ __launch_bounds__(256) void make_dinv(const int* __restrict__ degi,
                                                 float* __restrict__ dinv, int N) {
    int n = blockIdx.x * 256 + threadIdx.x;
    if (n < N) dinv[n] = rsqrtf((float)degi[n] + 1.0f);
}

// ---- 3-phase exclusive prefix sum over degi[N] -> rowptr[N+1] --------------
__global__ __launch_bounds__(256) void scan1(const int* __restrict__ deg, int N,
                                             int* __restrict__ bsum) {
    __shared__ int s[256];
    int t = threadIdx.x, base = blockIdx.x * 1024 + t * 4;
    int v = 0;
#pragma unroll
    for (int i = 0; i < 4; ++i) { int idx = base + i; if (idx < N) v += deg[idx]; }
    s[t] = v; __syncthreads();
    for (int off = 128; off > 0; off >>= 1) {
        if (t < off) s[t] += s[t + off];
        __syncthreads();
    }
    if (t == 0) bsum[blockIdx.x] = s[0];
}

__global__ __launch_bounds__(256) void scan2(int* __restrict__ bsum, int NB) {
    __shared__ int s[256];
    int t = threadIdx.x;
    int v = (t < NB) ? bsum[t] : 0;
    s[t] = v; __syncthreads();
    for (int off = 1; off < 256; off <<= 1) {
        int x = (t >= off) ? s[t - off] : 0;
        __syncthreads();
        s[t] += x;
        __syncthreads();
    }
    if (t < NB) bsum[t] = s[t] - v;   // exclusive
}

__global__ __launch_bounds__(256) void scan3(const int* __restrict__ deg,
                                             const int* __restrict__ bsumEx,
                                             int N, int E, int* __restrict__ rowptr) {
    __shared__ int s[256];
    int t = threadIdx.x, base = blockIdx.x * 1024 + t * 4;
    int v[4], sum = 0;
#pragma unroll
    for (int i = 0; i < 4; ++i) { int idx = base + i; v[i] = (idx < N) ? deg[idx] : 0; sum += v[i]; }
    s[t] = sum; __syncthreads();
    for (int off = 1; off < 256; off <<= 1) {
        int x = (t >= off) ? s[t - off] : 0;
        __syncthreads();
        s[t] += x;
        __syncthreads();
    }
    int run = bsumEx[blockIdx.x] + s[t] - sum;
#pragma unroll
    for (int i = 0; i < 4; ++i) {
        int idx = base + i;
        if (idx < N) rowptr[idx] = run;
        run += v[i];
    }
    if (blockIdx.x == 0 && t == 0) rowptr[N] = E;
}

// slot-fill: srcs grouped by target node (order within a node arbitrary)
__global__ __launch_bounds__(256) void fill_edges(const int* __restrict__ er,
                                                  const int* __restrict__ ec, int E,
                                                  const int* __restrict__ rowptr,
                                                  int* __restrict__ cursor,
                                                  int* __restrict__ srcs) {
    int e = blockIdx.x * 256 + threadIdx.x;
    if (e >= E) return;
    int r = er[e], c = ec[e];
    int pos = rowptr[c] + atomicAdd(&cursor[c], 1);
    srcs[pos] = r;
}

// P[n][:] = dinv[n] * ( sum_j dinv[srcs[j]]*H[srcs[j]][:] + dinv[n]*H[n][:] )
// H is bf16 (row = 256 B = 32 lanes x ushort4); accumulate fp32; P fp32 out.
__global__ __launch_bounds__(256) void pull_agg(const int* __restrict__ rowptr,
                                                const int* __restrict__ srcs,
                                                const float* __restrict__ dinv,
                                                const unsigned short* __restrict__ H,
                                                float* __restrict__ P, int N) {
    int node = blockIdx.x * 8 + (threadIdx.x >> 5);
    int lane = threadIdx.x & 31;
    if (node >= N) return;
    int j = rowptr[node], end = rowptr[node + 1];
    const ushort4* H2 = (const ushort4*)H;   // 32 ushort4 per row
    float sn = dinv[node];
    ushort4 hs = H2[(size_t)node * 32 + lane];
    float4 acc = make_float4(sn * bf2f(hs.x), sn * bf2f(hs.y),
                             sn * bf2f(hs.z), sn * bf2f(hs.w));
    for (; j + 8 <= end; j += 8) {
        int r[8]; float s[8]; ushort4 h[8];
#pragma unroll
        for (int t = 0; t < 8; ++t) r[t] = srcs[j + t];
#pragma unroll
        for (int t = 0; t < 8; ++t) s[t] = dinv[r[t]];
#pragma unroll
        for (int t = 0; t < 8; ++t) h[t] = H2[(size_t)r[t] * 32 + lane];
#pragma unroll
        for (int t = 0; t < 8; ++t) {
            acc.x += s[t] * bf2f(h[t].x); acc.y += s[t] * bf2f(h[t].y);
            acc.z += s[t] * bf2f(h[t].z); acc.w += s[t] * bf2f(h[t].w);
        }
    }
    for (; j < end; ++j) {
        int r0 = srcs[j];
        float s0 = dinv[r0];
        ushort4 h0 = H2[(size_t)r0 * 32 + lane];
        acc.x += s0 * bf2f(h0.x); acc.y += s0 * bf2f(h0.y);
        acc.z += s0 * bf2f(h0.z); acc.w += s0 * bf2f(h0.w);
    }
    acc.x *= sn; acc.y *= sn; acc.z *= sn; acc.w *= sn;
    ((float4*)P)[(size_t)node * 32 + lane] = acc;
}

// Hn[n][:] = bf16( relu( P[n][:] @ W + bias ) ).  128 nodes x 128 cols/block,
// thread = 8 nodes x 8 cols. P fp32 in, Hn bf16 out (different buffers).
__global__ __launch_bounds__(256) void gemm_agg(const float* __restrict__ P,
                                                const float* __restrict__ W,
                                                const float* __restrict__ bias,
                                                unsigned short* __restrict__ Hn, int N) {
    __shared__ __align__(16) float sW[32 * 128];
    __shared__ __align__(16) float sA[32 * SA_PITCH];

    const int tid = threadIdx.x;
    const int tx = tid & 15;   // cols 8*tx .. 8*tx+7
    const int ty = tid >> 4;   // nodes 8*ty .. 8*ty+7
    const int n0 = blockIdx.x * 128;

    float acc[8][8];
#pragma unroll
    for (int i = 0; i < 8; ++i)
#pragma unroll
        for (int j = 0; j < 8; ++j) acc[i][j] = 0.0f;

    const float4* P4 = (const float4*)P;
    const float4* W4 = (const float4*)W;

    for (int kc = 0; kc < 4; ++kc) {
#pragma unroll
        for (int i = 0; i < 4; ++i) {
            int f = tid + i * 256;
            int r = f >> 5, c4 = f & 31;
            ((float4*)sW)[r * 32 + c4] = W4[(kc * 32 + r) * 32 + c4];
        }
#pragma unroll
        for (int i = 0; i < 4; ++i) {
            int f = tid + i * 256;
            int n = f >> 3, c4 = f & 7;
            int node = n0 + n;
            float4 a = (node < N) ? P4[(size_t)node * 32 + kc * 8 + c4]
                                  : make_float4(0.f, 0.f, 0.f, 0.f);
            int kl = c4 * 4;
            sA[(kl + 0) * SA_PITCH + n] = a.x;
            sA[(kl + 1) * SA_PITCH + n] = a.y;
            sA[(kl + 2) * SA_PITCH + n] = a.z;
            sA[(kl + 3) * SA_PITCH + n] = a.w;
        }
        __syncthreads();

#pragma unroll 4
        for (int k = 0; k < 32; ++k) {
            float a_[8];
#pragma unroll
            for (int i = 0; i < 8; ++i) a_[i] = sA[k * SA_PITCH + 8 * ty + i];
            const float4 w0 = *(const float4*)(sW + k * 128 + 8 * tx);
            const float4 w1 = *(const float4*)(sW + k * 128 + 8 * tx + 4);
            const float w_[8] = {w0.x, w0.y, w0.z, w0.w, w1.x, w1.y, w1.z, w1.w};
#pragma unroll
            for (int i = 0; i < 8; ++i)
#pragma unroll
                for (int j = 0; j < 8; ++j) acc[i][j] += a_[i] * w_[j];
        }
        __syncthreads();
    }

    const float4 b0 = ((const float4*)bias)[2 * tx];
    const float4 b1 = ((const float4*)bias)[2 * tx + 1];
#pragma unroll
    for (int i = 0; i < 8; ++i) {
        int node = n0 + 8 * ty + i;
        if (node < N) {
            ushort4 o0, o1;
            o0.x = f2bf(fmaxf(acc[i][0] + b0.x, 0.f));
            o0.y = f2bf(fmaxf(acc[i][1] + b0.y, 0.f));
            o0.z = f2bf(fmaxf(acc[i][2] + b0.z, 0.f));
            o0.w = f2bf(fmaxf(acc[i][3] + b0.w, 0.f));
            o1.x = f2bf(fmaxf(acc[i][4] + b1.x, 0.f));
            o1.y = f2bf(fmaxf(acc[i][5] + b1.y, 0.f));
            o1.z = f2bf(fmaxf(acc[i][6] + b1.z, 0.f));
            o1.w = f2bf(fmaxf(acc[i][7] + b1.w, 0.f));
            ((ushort4*)Hn)[(size_t)node * 32 + 2 * tx] = o0;
            ((ushort4*)Hn)[(size_t)node * 32 + 2 * tx + 1] = o1;
        }
    }
}

// dots[n] = H[n][:] . Wl  (H bf16) — one wave per node, no atomics
__global__ __launch_bounds__(256) void node_dot(const unsigned short* __restrict__ H,
                                                const float* __restrict__ Wl,
                                                float* __restrict__ dots, int N) {
    long long gt = (long long)blockIdx.x * 256 + threadIdx.x;
    int n = (int)(gt >> 6);
    int lane = (int)(gt & 63);
    if (n >= N) return;
    ushort2 hv = ((const ushort2*)H)[(size_t)n * 64 + lane];
    float v = bf2f(hv.x) * Wl[2 * lane] + bf2f(hv.y) * Wl[2 * lane + 1];
#pragma unroll
    for (int off = 32; off > 0; off >>= 1) v += __shfl_down(v, off, 64);
    if (lane == 0) dots[n] = v;
}

// one block per graph: binary-search node range in sorted batch, mean, +bl
__global__ __launch_bounds__(256) void pool_graphs(const float* __restrict__ dots,
                                                   const int* __restrict__ batch, int N,
                                                   const float* __restrict__ bl,
                                                   float* __restrict__ out) {
    __shared__ int bounds[2];
    __shared__ float red[4];
    const int g = blockIdx.x;
    const int t = threadIdx.x;
    if (t < 2) {
        int key = g + t;             // lower_bound(batch, key)
        int lo = 0, hi = N;
        while (lo < hi) {
            int mid = (lo + hi) >> 1;
            if (batch[mid] < key) lo = mid + 1; else hi = mid;
        }
        bounds[t] = lo;
    }
    __syncthreads();
    const int lo = bounds[0], hi = bounds[1];
    float s = 0.f;
    for (int i = lo + t; i < hi; i += 256) s += dots[i];
#pragma unroll
    for (int off = 32; off > 0; off >>= 1) s += __shfl_down(s, off, 64);
    if ((t & 63) == 0) red[t >> 6] = s;
    __syncthreads();
    if (t == 0) {
        float tot = red[0] + red[1] + red[2] + red[3];
        int cnt = hi - lo;
        out[g] = tot / (float)(cnt > 0 ? cnt : 1) + bl[0];
    }
}

extern "C" void kernel_launch(void* const* d_in, const int* in_sizes, int n_in,
                              void* d_out, int out_size, void* d_ws, size_t ws_size,
                              hipStream_t stream) {
    const float* x     = (const float*)d_in[0];
    const int*   eidx  = (const int*)d_in[1];    // int32 (harness converts int64)
    const int*   batch = (const int*)d_in[2];
    const float* Ws    = (const float*)d_in[3];
    const float* bs    = (const float*)d_in[4];
    const float* Wl    = (const float*)d_in[5];
    const float* bl    = (const float*)d_in[6];
    (void)n_in; (void)out_size;

    const int N = in_sizes[0] / D;
    const int E = in_sizes[1] / 2;
    const int* er = eidx;       // sources
    const int* ec = eidx + E;   // targets

    // ---- workspace carve ----
    const size_t pBytes = (size_t)N * D * sizeof(float);          // 51.2 MB fp32 P
    const size_t hBytes = (size_t)N * D * sizeof(unsigned short); // 25.6 MB bf16 H
    const int Npad = (N + 63) & ~63;
    auto al = [](size_t v) { return (v + 255) & ~(size_t)255; };
    char* base = (char*)d_ws;
    size_t off = 0;

    float* P = (float*)base;                 off = al(pBytes);
    // zero-block: degi, cursor (contiguous -> one zero kernel)
    int*   degi   = (int*)(base + off);
    int*   cursor = degi + Npad;
    const int zeroInts = 2 * Npad;
    off = al(off + (size_t)zeroInts * sizeof(int));
    float* dinv   = (float*)(base + off);    off = al(off + (size_t)Npad * sizeof(float));
    float* dots   = (float*)(base + off);    off = al(off + (size_t)Npad * sizeof(float));
    int*   rowptr = (int*)(base + off);      off = al(off + (size_t)(Npad + 64) * sizeof(int));
    int*   bsum   = (int*)(base + off);      off = al(off + 256 * sizeof(int));
    int*   srcs   = (int*)(base + off);      off = al(off + (size_t)E * sizeof(int));
    unsigned short* Hb0 = (unsigned short*)(base + off);  off = al(off + hBytes);

    // second bf16 buffer: in ws if it fits, else reuse x's 51.2 MB input buffer
    const bool twoBuf = ws_size >= off + hBytes;
    unsigned short* Hb1 = twoBuf ? (unsigned short*)(base + off)
                                 : (unsigned short*)d_in[0];
    unsigned short* hb[2] = { Hb0, Hb1 };

    // ---- cast x -> bf16 (before anything may touch x's buffer) ----
    const int n4 = N * D / 4;
    cast_bf16<<<(n4 + 255) / 256, 256, 0, stream>>>((const float4*)x, (ushort4*)Hb0, n4);

    // ---- CSR build (once; reused by all 4 layers) ----
    zero_i4<<<(zeroInts / 4 + 255) / 256, 256, 0, stream>>>((int4*)degi, zeroInts / 4);
    count_deg<<<(E + 255) / 256, 256, 0, stream>>>(ec, E, degi);
    make_dinv<<<(N + 255) / 256, 256, 0, stream>>>(degi, dinv, N);
    const int NB = (N + 1023) / 1024;
    scan1<<<NB, 256, 0, stream>>>(degi, N, bsum);
    scan2<<<1, 256, 0, stream>>>(bsum, NB);
    scan3<<<NB, 256, 0, stream>>>(degi, bsum, N, E, rowptr);
    fill_edges<<<(E + 255) / 256, 256, 0, stream>>>(er, ec, E, rowptr, cursor, srcs);

    // ---- 4 layers: pull (bf16 gather -> fp32 P) -> gemm (fp32 -> bf16) ----
    for (int i = 0; i < 4; ++i) {
        const unsigned short* Hc = hb[i & 1];
        unsigned short* Hn = hb[(i + 1) & 1];
        pull_agg<<<(N + 7) / 8, 256, 0, stream>>>(rowptr, srcs, dinv, Hc, P, N);
        gemm_agg<<<(N + 127) / 128, 256, 0, stream>>>(P, Ws + (size_t)i * D * D,
                                                      bs + (size_t)i * D, Hn, N);
    }

    // ---- mean pool + linear head (final features in hb[0]) ----
    long long tot = (long long)N * 64;
    node_dot<<<(int)((tot + 255) / 256), 256, 0, stream>>>(hb[0], Wl, dots, N);
    pool_graphs<<<NGRAPH, 256, 0, stream>>>(dots, batch, N, bl, (float*)d_out);
}

// Round 9
// 707.299 us; speedup vs baseline: 1.4674x; 1.1199x over previous
//
#include <hip/hip_runtime.h>

// ---------------------------------------------------------------------------
// GCN forward, reassociated: per layer h = relu( (A_hat h) W + b ).
// R8 lessons: pull is L2-miss/fabric-throughput bound (bytes are the lever ->
// bf16 features); fp32 vector GEMM ran at ~41% of VALU peak and ~200us total.
// R9: GEMM moves to bf16 MFMA (16x16x32): pull emits bf16 P, W pre-cast to
// transposed bf16 Wt[c][k] once per launch; gemm_mfma needs no LDS/barriers
// (A-frags 16B/lane from global, B-frags 16B/lane from L2-resident Wt),
// fp32 accumulate, bias+relu fp32, bf16 out. C/D layout: col=lane&15,
// row=(lane>>4)*4+reg (verified mapping).
// Kept: CSR (srcs only) built once; atomic-free two-stage pooling.
// NOTE: harness delivers integer inputs as int32 (edge_index/batch: int*).
// ---------------------------------------------------------------------------

constexpr int D = 128;
constexpr int NGRAPH = 512;

typedef __attribute__((ext_vector_type(8))) short bf16x8;
typedef __attribute__((ext_vector_type(4))) float f32x4;

__device__ __forceinline__ float bf2f(unsigned short b) {
    return __uint_as_float(((unsigned int)b) << 16);
}
__device__ __forceinline__ unsigned short f2bf(float f) {   // round-to-nearest-even
    unsigned int u = __float_as_uint(f);
    u += 0x7FFFu + ((u >> 16) & 1u);
    return (unsigned short)(u >> 16);
}

__global__ __launch_bounds__(256) void zero_i4(int4* __restrict__ p, int n4) {
    int i = blockIdx.x * 256 + threadIdx.x;
    if (i < n4) p[i] = make_int4(0, 0, 0, 0);
}

// x fp32 -> bf16 feature buffer
__global__ __launch_bounds__(256) void cast_bf16(const float4* __restrict__ x4,
                                                 ushort4* __restrict__ hb, int n4) {
    int i = blockIdx.x * 256 + threadIdx.x;
    if (i >= n4) return;
    float4 v = x4[i];
    ushort4 o;
    o.x = f2bf(v.x); o.y = f2bf(v.y); o.z = f2bf(v.z); o.w = f2bf(v.w);
    hb[i] = o;
}

// Ws fp32 [4][k][c] -> Wt bf16 [4][c][k]  (transposed for MFMA B-fragments)
__global__ __launch_bounds__(256) void cast_w(const float* __restrict__ W,
                                              unsigned short* __restrict__ Wt) {
    int idx = blockIdx.x * 256 + threadIdx.x;   // 4*128*128 = 65536
    int i = idx >> 14;
    int rem = idx & 16383;
    int k = rem >> 7, c = rem & 127;
    Wt[(i << 14) + c * 128 + k] = f2bf(W[idx]);
}

// degi[c] += 1 per incoming edge (self-loop +1 added in make_dinv)
__global__ __launch_bounds__(256) void count_deg(const int* __restrict__ col,
                                                 int E, int* __restrict__ degi) {
    int e = blockIdx.x * 256 + threadIdx.x;
    if (e < E) atomicAdd(&degi[col[e]], 1);
}

__global__ __launch_bounds__(256) void make_dinv(const int* __restrict__ degi,
                                                 float* __restrict__ dinv, int N) {
    int n = blockIdx.x * 256 + threadIdx.x;
    if (n < N) dinv[n] = rsqrtf((float)degi[n] + 1.0f);
}

// ---- 3-phase exclusive prefix sum over degi[N] -> rowptr[N+1] --------------
__global__ __launch_bounds__(256) void scan1(const int* __restrict__ deg, int N,
                                             int* __restrict__ bsum) {
    __shared__ int s[256];
    int t = threadIdx.x, base = blockIdx.x * 1024 + t * 4;
    int v = 0;
#pragma unroll
    for (int i = 0; i < 4; ++i) { int idx = base + i; if (idx < N) v += deg[idx]; }
    s[t] = v; __syncthreads();
    for (int off = 128; off > 0; off >>= 1) {
        if (t < off) s[t] += s[t + off];
        __syncthreads();
    }
    if (t == 0) bsum[blockIdx.x] = s[0];
}

__global__ __launch_bounds__(256) void scan2(int* __restrict__ bsum, int NB) {
    __shared__ int s[256];
    int t = threadIdx.x;
    int v = (t < NB) ? bsum[t] : 0;
    s[t] = v; __syncthreads();
    for (int off = 1; off < 256; off <<= 1) {
        int x = (t >= off) ? s[t - off] : 0;
        __syncthreads();
        s[t] += x;
        __syncthreads();
    }
    if (t < NB) bsum[t] = s[t] - v;   // exclusive
}

__global__ __launch_bounds__(256) void scan3(const int* __restrict__ deg,
                                             const int* __restrict__ bsumEx,
                                             int N, int E, int* __restrict__ rowptr) {
    __shared__ int s[256];
    int t = threadIdx.x, base = blockIdx.x * 1024 + t * 4;
    int v[4], sum = 0;
#pragma unroll
    for (int i = 0; i < 4; ++i) { int idx = base + i; v[i] = (idx < N) ? deg[idx] : 0; sum += v[i]; }
    s[t] = sum; __syncthreads();
    for (int off = 1; off < 256; off <<= 1) {
        int x = (t >= off) ? s[t - off] : 0;
        __syncthreads();
        s[t] += x;
        __syncthreads();
    }
    int run = bsumEx[blockIdx.x] + s[t] - sum;
#pragma unroll
    for (int i = 0; i < 4; ++i) {
        int idx = base + i;
        if (idx < N) rowptr[idx] = run;
        run += v[i];
    }
    if (blockIdx.x == 0 && t == 0) rowptr[N] = E;
}

// slot-fill: srcs grouped by target node (order within a node arbitrary)
__global__ __launch_bounds__(256) void fill_edges(const int* __restrict__ er,
                                                  const int* __restrict__ ec, int E,
                                                  const int* __restrict__ rowptr,
                                                  int* __restrict__ cursor,
                                                  int* __restrict__ srcs) {
    int e = blockIdx.x * 256 + threadIdx.x;
    if (e >= E) return;
    int r = er[e], c = ec[e];
    int pos = rowptr[c] + atomicAdd(&cursor[c], 1);
    srcs[pos] = r;
}

// Pb[n][:] = bf16( dinv[n]*( sum_j dinv[srcs[j]]*H[srcs[j]][:] + dinv[n]*H[n][:] ) )
// H bf16 in, fp32 accumulate, bf16 out. Half-wave per node, 8-edge batches.
__global__ __launch_bounds__(256) void pull_agg(const int* __restrict__ rowptr,
                                                const int* __restrict__ srcs,
                                                const float* __restrict__ dinv,
                                                const unsigned short* __restrict__ H,
                                                unsigned short* __restrict__ Pb, int N) {
    int node = blockIdx.x * 8 + (threadIdx.x >> 5);
    int lane = threadIdx.x & 31;
    if (node >= N) return;
    int j = rowptr[node], end = rowptr[node + 1];
    const ushort4* H2 = (const ushort4*)H;   // 32 ushort4 per row
    float sn = dinv[node];
    ushort4 hs = H2[(size_t)node * 32 + lane];
    float4 acc = make_float4(sn * bf2f(hs.x), sn * bf2f(hs.y),
                             sn * bf2f(hs.z), sn * bf2f(hs.w));
    for (; j + 8 <= end; j += 8) {
        int r[8]; float s[8]; ushort4 h[8];
#pragma unroll
        for (int t = 0; t < 8; ++t) r[t] = srcs[j + t];
#pragma unroll
        for (int t = 0; t < 8; ++t) s[t] = dinv[r[t]];
#pragma unroll
        for (int t = 0; t < 8; ++t) h[t] = H2[(size_t)r[t] * 32 + lane];
#pragma unroll
        for (int t = 0; t < 8; ++t) {
            acc.x += s[t] * bf2f(h[t].x); acc.y += s[t] * bf2f(h[t].y);
            acc.z += s[t] * bf2f(h[t].z); acc.w += s[t] * bf2f(h[t].w);
        }
    }
    for (; j < end; ++j) {
        int r0 = srcs[j];
        float s0 = dinv[r0];
        ushort4 h0 = H2[(size_t)r0 * 32 + lane];
        acc.x += s0 * bf2f(h0.x); acc.y += s0 * bf2f(h0.y);
        acc.z += s0 * bf2f(h0.z); acc.w += s0 * bf2f(h0.w);
    }
    ushort4 o;
    o.x = f2bf(sn * acc.x); o.y = f2bf(sn * acc.y);
    o.z = f2bf(sn * acc.z); o.w = f2bf(sn * acc.w);
    ((ushort4*)Pb)[(size_t)node * 32 + lane] = o;
}

// Hn = bf16( relu( Pb @ W + bias ) ) via 16x16x32 bf16 MFMA.
// Block = 4 waves; wave = 16 rows x 128 cols (8 col-tiles x 4 K-chunks).
// A-frag: lane -> A[m=lane&15][k=quad*8+j] = 16B global load from Pb row.
// B-frag: lane -> B[k=quad*8+j][n=lane&15] = 16B load from Wt[c][k].
// C/D: col=lane&15, row=quad*4+reg.  No LDS, no barriers.
__global__ __launch_bounds__(256) void gemm_mfma(const unsigned short* __restrict__ Pb,
                                                 const unsigned short* __restrict__ Wt,
                                                 const float* __restrict__ bias,
                                                 unsigned short* __restrict__ Hn, int N) {
    const int wave = threadIdx.x >> 6;
    const int lane = threadIdx.x & 63;
    const int row16 = lane & 15;
    const int quad = lane >> 4;
    const int r0 = blockIdx.x * 64 + wave * 16;

    // A-fragments for all 4 K-chunks (rows guaranteed < Npad allocation)
    const bf16x8* Prow = (const bf16x8*)(Pb + (size_t)(r0 + row16) * 128);
    bf16x8 a[4];
#pragma unroll
    for (int kc = 0; kc < 4; ++kc) a[kc] = Prow[kc * 4 + quad];

#pragma unroll
    for (int ct = 0; ct < 8; ++ct) {
        const int col = ct * 16 + row16;
        const bf16x8* wc = (const bf16x8*)(Wt + (size_t)col * 128);
        f32x4 acc = {0.f, 0.f, 0.f, 0.f};
#pragma unroll
        for (int kc = 0; kc < 4; ++kc) {
            acc = __builtin_amdgcn_mfma_f32_16x16x32_bf16(a[kc], wc[kc * 4 + quad],
                                                          acc, 0, 0, 0);
        }
        const float bv = bias[col];
#pragma unroll
        for (int i = 0; i < 4; ++i) {
            int row = r0 + quad * 4 + i;
            if (row < N)
                Hn[(size_t)row * 128 + col] = f2bf(fmaxf(acc[i] + bv, 0.f));
        }
    }
}

// dots[n] = H[n][:] . Wl  (H bf16) — one wave per node, no atomics
__global__ __launch_bounds__(256) void node_dot(const unsigned short* __restrict__ H,
                                                const float* __restrict__ Wl,
                                                float* __restrict__ dots, int N) {
    long long gt = (long long)blockIdx.x * 256 + threadIdx.x;
    int n = (int)(gt >> 6);
    int lane = (int)(gt & 63);
    if (n >= N) return;
    ushort2 hv = ((const ushort2*)H)[(size_t)n * 64 + lane];
    float v = bf2f(hv.x) * Wl[2 * lane] + bf2f(hv.y) * Wl[2 * lane + 1];
#pragma unroll
    for (int off = 32; off > 0; off >>= 1) v += __shfl_down(v, off, 64);
    if (lane == 0) dots[n] = v;
}

// one block per graph: binary-search node range in sorted batch, mean, +bl
__global__ __launch_bounds__(256) void pool_graphs(const float* __restrict__ dots,
                                                   const int* __restrict__ batch, int N,
                                                   const float* __restrict__ bl,
                                                   float* __restrict__ out) {
    __shared__ int bounds[2];
    __shared__ float red[4];
    const int g = blockIdx.x;
    const int t = threadIdx.x;
    if (t < 2) {
        int key = g + t;             // lower_bound(batch, key)
        int lo = 0, hi = N;
        while (lo < hi) {
            int mid = (lo + hi) >> 1;
            if (batch[mid] < key) lo = mid + 1; else hi = mid;
        }
        bounds[t] = lo;
    }
    __syncthreads();
    const int lo = bounds[0], hi = bounds[1];
    float s = 0.f;
    for (int i = lo + t; i < hi; i += 256) s += dots[i];
#pragma unroll
    for (int off = 32; off > 0; off >>= 1) s += __shfl_down(s, off, 64);
    if ((t & 63) == 0) red[t >> 6] = s;
    __syncthreads();
    if (t == 0) {
        float tot = red[0] + red[1] + red[2] + red[3];
        int cnt = hi - lo;
        out[g] = tot / (float)(cnt > 0 ? cnt : 1) + bl[0];
    }
}

extern "C" void kernel_launch(void* const* d_in, const int* in_sizes, int n_in,
                              void* d_out, int out_size, void* d_ws, size_t ws_size,
                              hipStream_t stream) {
    const float* x     = (const float*)d_in[0];
    const int*   eidx  = (const int*)d_in[1];    // int32 (harness converts int64)
    const int*   batch = (const int*)d_in[2];
    const float* Ws    = (const float*)d_in[3];
    const float* bs    = (const float*)d_in[4];
    const float* Wl    = (const float*)d_in[5];
    const float* bl    = (const float*)d_in[6];
    (void)n_in; (void)out_size;

    const int N = in_sizes[0] / D;
    const int E = in_sizes[1] / 2;
    const int* er = eidx;       // sources
    const int* ec = eidx + E;   // targets

    // ---- workspace carve ----
    const int Npad = (N + 63) & ~63;
    const size_t hBytes = (size_t)Npad * D * sizeof(unsigned short); // 25.6 MB bf16
    auto al = [](size_t v) { return (v + 255) & ~(size_t)255; };
    char* base = (char*)d_ws;
    size_t off = 0;

    unsigned short* Pb = (unsigned short*)base;  off = al(hBytes);
    // zero-block: degi, cursor (contiguous -> one zero kernel)
    int*   degi   = (int*)(base + off);
    int*   cursor = degi + Npad;
    const int zeroInts = 2 * Npad;
    off = al(off + (size_t)zeroInts * sizeof(int));
    float* dinv   = (float*)(base + off);    off = al(off + (size_t)Npad * sizeof(float));
    float* dots   = (float*)(base + off);    off = al(off + (size_t)Npad * sizeof(float));
    int*   rowptr = (int*)(base + off);      off = al(off + (size_t)(Npad + 64) * sizeof(int));
    int*   bsum   = (int*)(base + off);      off = al(off + 256 * sizeof(int));
    int*   srcs   = (int*)(base + off);      off = al(off + (size_t)E * sizeof(int));
    unsigned short* Wt = (unsigned short*)(base + off);   off = al(off + 4 * 128 * 128 * sizeof(unsigned short));
    unsigned short* Hb0 = (unsigned short*)(base + off);  off = al(off + hBytes);

    // second bf16 buffer: in ws if it fits, else reuse x's 51.2 MB input buffer
    const bool twoBuf = ws_size >= off + hBytes;
    unsigned short* Hb1 = twoBuf ? (unsigned short*)(base + off)
                                 : (unsigned short*)d_in[0];
    unsigned short* hb[2] = { Hb0, Hb1 };

    // ---- casts (x before anything may reuse its buffer; W -> transposed bf16) ----
    const int n4 = N * D / 4;
    cast_bf16<<<(n4 + 255) / 256, 256, 0, stream>>>((const float4*)x, (ushort4*)Hb0, n4);
    cast_w<<<256, 256, 0, stream>>>(Ws, Wt);

    // ---- CSR build (once; reused by all 4 layers) ----
    zero_i4<<<(zeroInts / 4 + 255) / 256, 256, 0, stream>>>((int4*)degi, zeroInts / 4);
    count_deg<<<(E + 255) / 256, 256, 0, stream>>>(ec, E, degi);
    make_dinv<<<(N + 255) / 256, 256, 0, stream>>>(degi, dinv, N);
    const int NB = (N + 1023) / 1024;
    scan1<<<NB, 256, 0, stream>>>(degi, N, bsum);
    scan2<<<1, 256, 0, stream>>>(bsum, NB);
    scan3<<<NB, 256, 0, stream>>>(degi, bsum, N, E, rowptr);
    fill_edges<<<(E + 255) / 256, 256, 0, stream>>>(er, ec, E, rowptr, cursor, srcs);

    // ---- 4 layers: pull (bf16 gather -> bf16 Pb) -> MFMA gemm (-> bf16 Hn) ----
    for (int i = 0; i < 4; ++i) {
        const unsigned short* Hc = hb[i & 1];
        unsigned short* Hn = hb[(i + 1) & 1];
        pull_agg<<<(N + 7) / 8, 256, 0, stream>>>(rowptr, srcs, dinv, Hc, Pb, N);
        gemm_mfma<<<(N + 63) / 64, 256, 0, stream>>>(Pb, Wt + (size_t)i * D * D,
                                                     bs + (size_t)i * D, Hn, N);
    }

    // ---- mean pool + linear head (final features in hb[0]) ----
    long long tot = (long long)N * 64;
    node_dot<<<(int)((tot + 255) / 256), 256, 0, stream>>>(hb[0], Wl, dots, N);
    pool_graphs<<<NGRAPH, 256, 0, stream>>>(dots, batch, N, bl, (float*)d_out);
}

// Round 10
// 582.215 us; speedup vs baseline: 1.7827x; 1.2148x over previous
//
#include <hip/hip_runtime.h>

// ---------------------------------------------------------------------------
// GCN forward, reassociated: per layer h = relu( (A_hat h) W + b ).
// R9 lesson: one-pass CSR slot-fill writes 107MB HBM for a 6.4MB payload
// (random 4B scatters; node slots filled from all 8 XCDs -> partial lines).
// R10: two-pass binned build. Bucket = c>>9 (512 nodes) so ALL edges of a
// node share a bucket:
//   hist_pass -> bucket_scan -> scatter_pairs (LDS-staged, coalesced segment
//   writes) -> fill_csr (per-bucket block: LDS hist+scan gives rowptr, dinv,
//   and slot cursors with NO global atomics; srcs writes in a 32KB window).
// Replaces count_deg/make_dinv/scan1-3/fill_edges.
// Kept: bf16 features (gather is byte-bound), MFMA GEMM, atomic-free pooling.
// NOTE: harness delivers integer inputs as int32 (edge_index/batch: int*).
// ---------------------------------------------------------------------------

constexpr int D = 128;
constexpr int NGRAPH = 512;
constexpr int CHUNK = 4096;       // edges per scatter block
constexpr int BSH = 9;            // 512 nodes per bucket

typedef __attribute__((ext_vector_type(8))) short bf16x8;
typedef __attribute__((ext_vector_type(4))) float f32x4;

__device__ __forceinline__ float bf2f(unsigned short b) {
    return __uint_as_float(((unsigned int)b) << 16);
}
__device__ __forceinline__ unsigned short f2bf(float f) {   // round-to-nearest-even
    unsigned int u = __float_as_uint(f);
    u += 0x7FFFu + ((u >> 16) & 1u);
    return (unsigned short)(u >> 16);
}

__global__ __launch_bounds__(256) void zero_i4(int4* __restrict__ p, int n4) {
    int i = blockIdx.x * 256 + threadIdx.x;
    if (i < n4) p[i] = make_int4(0, 0, 0, 0);
}

// x fp32 -> bf16 feature buffer
__global__ __launch_bounds__(256) void cast_bf16(const float4* __restrict__ x4,
                                                 ushort4* __restrict__ hb, int n4) {
    int i = blockIdx.x * 256 + threadIdx.x;
    if (i >= n4) return;
    float4 v = x4[i];
    ushort4 o;
    o.x = f2bf(v.x); o.y = f2bf(v.y); o.z = f2bf(v.z); o.w = f2bf(v.w);
    hb[i] = o;
}

// Ws fp32 [4][k][c] -> Wt bf16 [4][c][k]  (transposed for MFMA B-fragments)
__global__ __launch_bounds__(256) void cast_w(const float* __restrict__ W,
                                              unsigned short* __restrict__ Wt) {
    int idx = blockIdx.x * 256 + threadIdx.x;   // 4*128*128 = 65536
    int i = idx >> 14;
    int rem = idx & 16383;
    int k = rem >> 7, c = rem & 127;
    Wt[(i << 14) + c * 128 + k] = f2bf(W[idx]);
}

// ---- binned CSR build ------------------------------------------------------
// pass 1: global bucket histogram (LDS-aggregated)
__global__ __launch_bounds__(256) void hist_pass(const int* __restrict__ ec, int E,
                                                 int* __restrict__ bucketCnt) {
    __shared__ int h[256];
    const int t = threadIdx.x;
    h[t] = 0;
    __syncthreads();
    const int e0 = blockIdx.x * CHUNK;
    const int cnt = min(CHUNK, E - e0);
    for (int i = t; i < cnt; i += 256) atomicAdd(&h[ec[e0 + i] >> BSH], 1);
    __syncthreads();
    if (h[t]) atomicAdd(&bucketCnt[t], h[t]);
}

// pass 2: exclusive scan over 256 bucket counts -> bucketBase, globCursor
__global__ __launch_bounds__(256) void bucket_scan(const int* __restrict__ bucketCnt,
                                                   int* __restrict__ bucketBase,
                                                   int* __restrict__ globCursor) {
    __shared__ int s[256];
    const int t = threadIdx.x;
    int v = bucketCnt[t];
    s[t] = v; __syncthreads();
    for (int off = 1; off < 256; off <<= 1) {
        int x = (t >= off) ? s[t - off] : 0;
        __syncthreads();
        s[t] += x;
        __syncthreads();
    }
    int excl = s[t] - v;
    bucketBase[t] = excl;
    globCursor[t] = excl;
}

// pass 3: scatter (r,c) pairs into bucket-grouped array, LDS-staged & coalesced
__global__ __launch_bounds__(256) void scatter_pairs(const int* __restrict__ er,
                                                     const int* __restrict__ ec, int E,
                                                     int* __restrict__ globCursor,
                                                     int2* __restrict__ pairs) {
    __shared__ int h[256], lbase[256], cur[256], segd[256], s[256];
    __shared__ int2 stage[CHUNK];
    const int t = threadIdx.x;
    const int e0 = blockIdx.x * CHUNK;
    const int cnt = min(CHUNK, E - e0);

    h[t] = 0;
    __syncthreads();
    for (int i = t; i < cnt; i += 256) atomicAdd(&h[ec[e0 + i] >> BSH], 1);
    __syncthreads();
    // exclusive scan of h -> lbase
    int v = h[t];
    s[t] = v; __syncthreads();
    for (int off = 1; off < 256; off <<= 1) {
        int x = (t >= off) ? s[t - off] : 0;
        __syncthreads();
        s[t] += x;
        __syncthreads();
    }
    lbase[t] = s[t] - v;
    cur[t] = s[t] - v;
    // reserve contiguous global segment per bucket
    segd[t] = atomicAdd(&globCursor[t], v) - lbase[t];
    __syncthreads();
    // stage grouped by bucket
    for (int i = t; i < cnt; i += 256) {
        int c = ec[e0 + i];
        int b = c >> BSH;
        int p = atomicAdd(&cur[b], 1);
        stage[p] = make_int2(er[e0 + i], c);
    }
    __syncthreads();
    // copy out: consecutive LDS slots -> contiguous global segments
    for (int i = t; i < cnt; i += 256) {
        int2 pr = stage[i];
        int b = pr.y >> BSH;
        pairs[segd[b] + i] = pr;
    }
}

// pass 4: one block per bucket. Local 512-node histogram + scan in LDS ->
// rowptr, dinv, and slot fill with LDS cursors (no global atomics).
__global__ __launch_bounds__(256) void fill_csr(const int2* __restrict__ pairs,
                                                const int* __restrict__ bucketBase,
                                                const int* __restrict__ bucketCnt,
                                                int N, int E, int NBUCK,
                                                int* __restrict__ rowptr,
                                                float* __restrict__ dinv,
                                                int* __restrict__ srcs) {
    __shared__ int hist[512], lofs[512], s[256];
    const int t = threadIdx.x;
    const int b = blockIdx.x;
    const int c0 = b << BSH;
    const int base = bucketBase[b];
    const int cnt = bucketCnt[b];
    const int2* pp = pairs + base;

    hist[t] = 0; hist[t + 256] = 0;
    __syncthreads();
    for (int i = t; i < cnt; i += 256) atomicAdd(&hist[pp[i].y - c0], 1);
    __syncthreads();
    // exclusive scan of 512 via 256 threads (pairs)
    int a0 = hist[2 * t], a1 = hist[2 * t + 1];
    s[t] = a0 + a1; __syncthreads();
    for (int off = 1; off < 256; off <<= 1) {
        int x = (t >= off) ? s[t - off] : 0;
        __syncthreads();
        s[t] += x;
        __syncthreads();
    }
    int excl = s[t] - (a0 + a1);
    lofs[2 * t] = excl;
    lofs[2 * t + 1] = excl + a0;
    __syncthreads();
    // rowptr + dinv for this bucket's nodes
    const int nn = min(512, N - c0);
    for (int i = t; i < nn; i += 256) {
        rowptr[c0 + i] = base + lofs[i];
        dinv[c0 + i] = rsqrtf((float)hist[i] + 1.0f);
    }
    if (b == NBUCK - 1 && t == 0) rowptr[N] = E;
    __syncthreads();
    // fill slots: lofs doubles as per-node cursor
    for (int i = t; i < cnt; i += 256) {
        int2 pr = pp[i];
        int p = atomicAdd(&lofs[pr.y - c0], 1);
        srcs[base + p] = pr.x;
    }
}

// Pb[n][:] = bf16( dinv[n]*( sum_j dinv[srcs[j]]*H[srcs[j]][:] + dinv[n]*H[n][:] ) )
// H bf16 in, fp32 accumulate, bf16 out. Half-wave per node, 8-edge batches.
__global__ __launch_bounds__(256) void pull_agg(const int* __restrict__ rowptr,
                                                const int* __restrict__ srcs,
                                                const float* __restrict__ dinv,
                                                const unsigned short* __restrict__ H,
                                                unsigned short* __restrict__ Pb, int N) {
    int node = blockIdx.x * 8 + (threadIdx.x >> 5);
    int lane = threadIdx.x & 31;
    if (node >= N) return;
    int j = rowptr[node], end = rowptr[node + 1];
    const ushort4* H2 = (const ushort4*)H;   // 32 ushort4 per row
    float sn = dinv[node];
    ushort4 hs = H2[(size_t)node * 32 + lane];
    float4 acc = make_float4(sn * bf2f(hs.x), sn * bf2f(hs.y),
                             sn * bf2f(hs.z), sn * bf2f(hs.w));
    for (; j + 8 <= end; j += 8) {
        int r[8]; float s[8]; ushort4 h[8];
#pragma unroll
        for (int t = 0; t < 8; ++t) r[t] = srcs[j + t];
#pragma unroll
        for (int t = 0; t < 8; ++t) s[t] = dinv[r[t]];
#pragma unroll
        for (int t = 0; t < 8; ++t) h[t] = H2[(size_t)r[t] * 32 + lane];
#pragma unroll
        for (int t = 0; t < 8; ++t) {
            acc.x += s[t] * bf2f(h[t].x); acc.y += s[t] * bf2f(h[t].y);
            acc.z += s[t] * bf2f(h[t].z); acc.w += s[t] * bf2f(h[t].w);
        }
    }
    for (; j < end; ++j) {
        int r0 = srcs[j];
        float s0 = dinv[r0];
        ushort4 h0 = H2[(size_t)r0 * 32 + lane];
        acc.x += s0 * bf2f(h0.x); acc.y += s0 * bf2f(h0.y);
        acc.z += s0 * bf2f(h0.z); acc.w += s0 * bf2f(h0.w);
    }
    ushort4 o;
    o.x = f2bf(sn * acc.x); o.y = f2bf(sn * acc.y);
    o.z = f2bf(sn * acc.z); o.w = f2bf(sn * acc.w);
    ((ushort4*)Pb)[(size_t)node * 32 + lane] = o;
}

// Hn = bf16( relu( Pb @ W + bias ) ) via 16x16x32 bf16 MFMA.
// Block = 4 waves; wave = 16 rows x 128 cols. No LDS, no barriers.
// C/D: col=lane&15, row=(lane>>4)*4+reg (verified mapping).
__global__ __launch_bounds__(256) void gemm_mfma(const unsigned short* __restrict__ Pb,
                                                 const unsigned short* __restrict__ Wt,
                                                 const float* __restrict__ bias,
                                                 unsigned short* __restrict__ Hn, int N) {
    const int wave = threadIdx.x >> 6;
    const int lane = threadIdx.x & 63;
    const int row16 = lane & 15;
    const int quad = lane >> 4;
    const int r0 = blockIdx.x * 64 + wave * 16;

    const bf16x8* Prow = (const bf16x8*)(Pb + (size_t)(r0 + row16) * 128);
    bf16x8 a[4];
#pragma unroll
    for (int kc = 0; kc < 4; ++kc) a[kc] = Prow[kc * 4 + quad];

#pragma unroll
    for (int ct = 0; ct < 8; ++ct) {
        const int col = ct * 16 + row16;
        const bf16x8* wc = (const bf16x8*)(Wt + (size_t)col * 128);
        f32x4 acc = {0.f, 0.f, 0.f, 0.f};
#pragma unroll
        for (int kc = 0; kc < 4; ++kc) {
            acc = __builtin_amdgcn_mfma_f32_16x16x32_bf16(a[kc], wc[kc * 4 + quad],
                                                          acc, 0, 0, 0);
        }
        const float bv = bias[col];
#pragma unroll
        for (int i = 0; i < 4; ++i) {
            int row = r0 + quad * 4 + i;
            if (row < N)
                Hn[(size_t)row * 128 + col] = f2bf(fmaxf(acc[i] + bv, 0.f));
        }
    }
}

// dots[n] = H[n][:] . Wl  (H bf16) — one wave per node, no atomics
__global__ __launch_bounds__(256) void node_dot(const unsigned short* __restrict__ H,
                                                const float* __restrict__ Wl,
                                                float* __restrict__ dots, int N) {
    long long gt = (long long)blockIdx.x * 256 + threadIdx.x;
    int n = (int)(gt >> 6);
    int lane = (int)(gt & 63);
    if (n >= N) return;
    ushort2 hv = ((const ushort2*)H)[(size_t)n * 64 + lane];
    float v = bf2f(hv.x) * Wl[2 * lane] + bf2f(hv.y) * Wl[2 * lane + 1];
#pragma unroll
    for (int off = 32; off > 0; off >>= 1) v += __shfl_down(v, off, 64);
    if (lane == 0) dots[n] = v;
}

// one block per graph: binary-search node range in sorted batch, mean, +bl
__global__ __launch_bounds__(256) void pool_graphs(const float* __restrict__ dots,
                                                   const int* __restrict__ batch, int N,
                                                   const float* __restrict__ bl,
                                                   float* __restrict__ out) {
    __shared__ int bounds[2];
    __shared__ float red[4];
    const int g = blockIdx.x;
    const int t = threadIdx.x;
    if (t < 2) {
        int key = g + t;             // lower_bound(batch, key)
        int lo = 0, hi = N;
        while (lo < hi) {
            int mid = (lo + hi) >> 1;
            if (batch[mid] < key) lo = mid + 1; else hi = mid;
        }
        bounds[t] = lo;
    }
    __syncthreads();
    const int lo = bounds[0], hi = bounds[1];
    float s = 0.f;
    for (int i = lo + t; i < hi; i += 256) s += dots[i];
#pragma unroll
    for (int off = 32; off > 0; off >>= 1) s += __shfl_down(s, off, 64);
    if ((t & 63) == 0) red[t >> 6] = s;
    __syncthreads();
    if (t == 0) {
        float tot = red[0] + red[1] + red[2] + red[3];
        int cnt = hi - lo;
        out[g] = tot / (float)(cnt > 0 ? cnt : 1) + bl[0];
    }
}

extern "C" void kernel_launch(void* const* d_in, const int* in_sizes, int n_in,
                              void* d_out, int out_size, void* d_ws, size_t ws_size,
                              hipStream_t stream) {
    const float* x     = (const float*)d_in[0];
    const int*   eidx  = (const int*)d_in[1];    // int32 (harness converts int64)
    const int*   batch = (const int*)d_in[2];
    const float* Ws    = (const float*)d_in[3];
    const float* bs    = (const float*)d_in[4];
    const float* Wl    = (const float*)d_in[5];
    const float* bl    = (const float*)d_in[6];
    (void)n_in; (void)out_size;

    const int N = in_sizes[0] / D;
    const int E = in_sizes[1] / 2;
    const int* er = eidx;       // sources
    const int* ec = eidx + E;   // targets
    const int NBUCK = (N + 511) >> BSH;          // 512-node buckets (<= 256)
    const int NCHUNK = (E + CHUNK - 1) / CHUNK;

    // ---- workspace carve ----
    const int Npad = (N + 63) & ~63;
    const size_t hBytes = (size_t)Npad * D * sizeof(unsigned short); // 25.6 MB bf16
    auto al = [](size_t v) { return (v + 255) & ~(size_t)255; };
    char* base = (char*)d_ws;
    size_t off = 0;

    unsigned short* Pb = (unsigned short*)base;  off = al(hBytes);
    int2* pairs = (int2*)Pb;                     // aliases Pb (CSR build precedes layers)
    // zero-block: bucketCnt[256] + globCursor[256]
    int* bucketCnt  = (int*)(base + off);
    int* globCursor = bucketCnt + 256;
    off = al(off + 512 * sizeof(int));
    int*   bucketBase = (int*)(base + off);  off = al(off + 256 * sizeof(int));
    float* dinv   = (float*)(base + off);    off = al(off + (size_t)Npad * sizeof(float));
    float* dots   = (float*)(base + off);    off = al(off + (size_t)Npad * sizeof(float));
    int*   rowptr = (int*)(base + off);      off = al(off + (size_t)(Npad + 64) * sizeof(int));
    int*   srcs   = (int*)(base + off);      off = al(off + (size_t)E * sizeof(int));
    unsigned short* Wt = (unsigned short*)(base + off);   off = al(off + 4 * 128 * 128 * sizeof(unsigned short));
    unsigned short* Hb0 = (unsigned short*)(base + off);  off = al(off + hBytes);

    // second bf16 buffer: in ws if it fits, else reuse x's 51.2 MB input buffer
    const bool twoBuf = ws_size >= off + hBytes;
    unsigned short* Hb1 = twoBuf ? (unsigned short*)(base + off)
                                 : (unsigned short*)d_in[0];
    unsigned short* hb[2] = { Hb0, Hb1 };

    // ---- casts (x first: Hb1 may alias x's buffer) ----
    const int n4 = N * D / 4;
    cast_bf16<<<(n4 + 255) / 256, 256, 0, stream>>>((const float4*)x, (ushort4*)Hb0, n4);
    cast_w<<<256, 256, 0, stream>>>(Ws, Wt);

    // ---- binned CSR build (once; reused by all 4 layers) ----
    zero_i4<<<1, 256, 0, stream>>>((int4*)bucketCnt, 128);
    hist_pass<<<NCHUNK, 256, 0, stream>>>(ec, E, bucketCnt);
    bucket_scan<<<1, 256, 0, stream>>>(bucketCnt, bucketBase, globCursor);
    scatter_pairs<<<NCHUNK, 256, 0, stream>>>(er, ec, E, globCursor, pairs);
    fill_csr<<<NBUCK, 256, 0, stream>>>(pairs, bucketBase, bucketCnt, N, E, NBUCK,
                                        rowptr, dinv, srcs);

    // ---- 4 layers: pull (bf16 gather -> bf16 Pb) -> MFMA gemm (-> bf16 Hn) ----
    for (int i = 0; i < 4; ++i) {
        const unsigned short* Hc = hb[i & 1];
        unsigned short* Hn = hb[(i + 1) & 1];
        pull_agg<<<(N + 7) / 8, 256, 0, stream>>>(rowptr, srcs, dinv, Hc, Pb, N);
        gemm_mfma<<<(N + 63) / 64, 256, 0, stream>>>(Pb, Wt + (size_t)i * D * D,
                                                     bs + (size_t)i * D, Hn, N);
    }

    // ---- mean pool + linear head (final features in hb[0]) ----
    long long tot = (long long)N * 64;
    node_dot<<<(int)((tot + 255) / 256), 256, 0, stream>>>(hb[0], Wl, dots, N);
    pool_graphs<<<NGRAPH, 256, 0, stream>>>(dots, batch, N, bl, (float*)d_out);
}

// Round 11
// 569.302 us; speedup vs baseline: 1.8231x; 1.0227x over previous
//
#include <hip/hip_runtime.h>

// ---------------------------------------------------------------------------
// GCN forward, reassociated: per layer h = relu( (A_hat h) W + b ).
// R10 state: pull_agg (random bf16 row gather over CSR) is the structural
// wall: FETCH = 8 XCDs x |H| at ~3.3 TB/s — at its bf16 floor (fp8 would
// exceed the error budget). This round trims the rest:
//  - gemm_mfma epilogue: per-wave LDS staging -> coalesced ushort4 stores
//    (was 64 scattered 2B stores/lane).
//  - layer 4: head dot (h . Wl) fused into the gemm epilogue -> no Hn write,
//    node_dot kernel deleted.
//  - guards dropped: all row buffers sized to Npad.
// Kept: bf16 features, binned no-atomic CSR build, atomic-free pooling.
// NOTE: harness delivers integer inputs as int32 (edge_index/batch: int*).
// ---------------------------------------------------------------------------

constexpr int D = 128;
constexpr int NGRAPH = 512;
constexpr int CHUNK = 4096;       // edges per scatter block
constexpr int BSH = 9;            // 512 nodes per bucket
constexpr int TP = 132;           // epilogue LDS tile pitch (2-way bank alias = free)

typedef __attribute__((ext_vector_type(8))) short bf16x8;
typedef __attribute__((ext_vector_type(4))) float f32x4;

__device__ __forceinline__ float bf2f(unsigned short b) {
    return __uint_as_float(((unsigned int)b) << 16);
}
__device__ __forceinline__ unsigned short f2bf(float f) {   // round-to-nearest-even
    unsigned int u = __float_as_uint(f);
    u += 0x7FFFu + ((u >> 16) & 1u);
    return (unsigned short)(u >> 16);
}

__global__ __launch_bounds__(256) void zero_i4(int4* __restrict__ p, int n4) {
    int i = blockIdx.x * 256 + threadIdx.x;
    if (i < n4) p[i] = make_int4(0, 0, 0, 0);
}

// x fp32 -> bf16 feature buffer
__global__ __launch_bounds__(256) void cast_bf16(const float4* __restrict__ x4,
                                                 ushort4* __restrict__ hb, int n4) {
    int i = blockIdx.x * 256 + threadIdx.x;
    if (i >= n4) return;
    float4 v = x4[i];
    ushort4 o;
    o.x = f2bf(v.x); o.y = f2bf(v.y); o.z = f2bf(v.z); o.w = f2bf(v.w);
    hb[i] = o;
}

// Ws fp32 [4][k][c] -> Wt bf16 [4][c][k]  (transposed for MFMA B-fragments)
__global__ __launch_bounds__(256) void cast_w(const float* __restrict__ W,
                                              unsigned short* __restrict__ Wt) {
    int idx = blockIdx.x * 256 + threadIdx.x;   // 4*128*128 = 65536
    int i = idx >> 14;
    int rem = idx & 16383;
    int k = rem >> 7, c = rem & 127;
    Wt[(i << 14) + c * 128 + k] = f2bf(W[idx]);
}

// ---- binned CSR build ------------------------------------------------------
// pass 1: global bucket histogram (LDS-aggregated)
__global__ __launch_bounds__(256) void hist_pass(const int* __restrict__ ec, int E,
                                                 int* __restrict__ bucketCnt) {
    __shared__ int h[256];
    const int t = threadIdx.x;
    h[t] = 0;
    __syncthreads();
    const int e0 = blockIdx.x * CHUNK;
    const int cnt = min(CHUNK, E - e0);
    for (int i = t; i < cnt; i += 256) atomicAdd(&h[ec[e0 + i] >> BSH], 1);
    __syncthreads();
    if (h[t]) atomicAdd(&bucketCnt[t], h[t]);
}

// pass 2: exclusive scan over 256 bucket counts -> bucketBase, globCursor
__global__ __launch_bounds__(256) void bucket_scan(const int* __restrict__ bucketCnt,
                                                   int* __restrict__ bucketBase,
                                                   int* __restrict__ globCursor) {
    __shared__ int s[256];
    const int t = threadIdx.x;
    int v = bucketCnt[t];
    s[t] = v; __syncthreads();
    for (int off = 1; off < 256; off <<= 1) {
        int x = (t >= off) ? s[t - off] : 0;
        __syncthreads();
        s[t] += x;
        __syncthreads();
    }
    int excl = s[t] - v;
    bucketBase[t] = excl;
    globCursor[t] = excl;
}

// pass 3: scatter (r,c) pairs into bucket-grouped array, LDS-staged & coalesced
__global__ __launch_bounds__(256) void scatter_pairs(const int* __restrict__ er,
                                                     const int* __restrict__ ec, int E,
                                                     int* __restrict__ globCursor,
                                                     int2* __restrict__ pairs) {
    __shared__ int h[256], lbase[256], cur[256], segd[256], s[256];
    __shared__ int2 stage[CHUNK];
    const int t = threadIdx.x;
    const int e0 = blockIdx.x * CHUNK;
    const int cnt = min(CHUNK, E - e0);

    h[t] = 0;
    __syncthreads();
    for (int i = t; i < cnt; i += 256) atomicAdd(&h[ec[e0 + i] >> BSH], 1);
    __syncthreads();
    int v = h[t];
    s[t] = v; __syncthreads();
    for (int off = 1; off < 256; off <<= 1) {
        int x = (t >= off) ? s[t - off] : 0;
        __syncthreads();
        s[t] += x;
        __syncthreads();
    }
    lbase[t] = s[t] - v;
    cur[t] = s[t] - v;
    segd[t] = atomicAdd(&globCursor[t], v) - lbase[t];
    __syncthreads();
    for (int i = t; i < cnt; i += 256) {
        int c = ec[e0 + i];
        int b = c >> BSH;
        int p = atomicAdd(&cur[b], 1);
        stage[p] = make_int2(er[e0 + i], c);
    }
    __syncthreads();
    for (int i = t; i < cnt; i += 256) {
        int2 pr = stage[i];
        int b = pr.y >> BSH;
        pairs[segd[b] + i] = pr;
    }
}

// pass 4: one block per bucket. LDS hist+scan -> rowptr, dinv, slot fill.
__global__ __launch_bounds__(256) void fill_csr(const int2* __restrict__ pairs,
                                                const int* __restrict__ bucketBase,
                                                const int* __restrict__ bucketCnt,
                                                int N, int E, int NBUCK,
                                                int* __restrict__ rowptr,
                                                float* __restrict__ dinv,
                                                int* __restrict__ srcs) {
    __shared__ int hist[512], lofs[512], s[256];
    const int t = threadIdx.x;
    const int b = blockIdx.x;
    const int c0 = b << BSH;
    const int base = bucketBase[b];
    const int cnt = bucketCnt[b];
    const int2* pp = pairs + base;

    hist[t] = 0; hist[t + 256] = 0;
    __syncthreads();
    for (int i = t; i < cnt; i += 256) atomicAdd(&hist[pp[i].y - c0], 1);
    __syncthreads();
    int a0 = hist[2 * t], a1 = hist[2 * t + 1];
    s[t] = a0 + a1; __syncthreads();
    for (int off = 1; off < 256; off <<= 1) {
        int x = (t >= off) ? s[t - off] : 0;
        __syncthreads();
        s[t] += x;
        __syncthreads();
    }
    int excl = s[t] - (a0 + a1);
    lofs[2 * t] = excl;
    lofs[2 * t + 1] = excl + a0;
    __syncthreads();
    const int nn = min(512, N - c0);
    for (int i = t; i < nn; i += 256) {
        rowptr[c0 + i] = base + lofs[i];
        dinv[c0 + i] = rsqrtf((float)hist[i] + 1.0f);
    }
    if (b == NBUCK - 1 && t == 0) rowptr[N] = E;
    __syncthreads();
    for (int i = t; i < cnt; i += 256) {
        int2 pr = pp[i];
        int p = atomicAdd(&lofs[pr.y - c0], 1);
        srcs[base + p] = pr.x;
    }
}

// Pb[n][:] = bf16( dinv[n]*( sum_j dinv[srcs[j]]*H[srcs[j]][:] + dinv[n]*H[n][:] ) )
__global__ __launch_bounds__(256) void pull_agg(const int* __restrict__ rowptr,
                                                const int* __restrict__ srcs,
                                                const float* __restrict__ dinv,
                                                const unsigned short* __restrict__ H,
                                                unsigned short* __restrict__ Pb, int N) {
    int node = blockIdx.x * 8 + (threadIdx.x >> 5);
    int lane = threadIdx.x & 31;
    if (node >= N) return;
    int j = rowptr[node], end = rowptr[node + 1];
    const ushort4* H2 = (const ushort4*)H;   // 32 ushort4 per row
    float sn = dinv[node];
    ushort4 hs = H2[(size_t)node * 32 + lane];
    float4 acc = make_float4(sn * bf2f(hs.x), sn * bf2f(hs.y),
                             sn * bf2f(hs.z), sn * bf2f(hs.w));
    for (; j + 8 <= end; j += 8) {
        int r[8]; float s[8]; ushort4 h[8];
#pragma unroll
        for (int t = 0; t < 8; ++t) r[t] = srcs[j + t];
#pragma unroll
        for (int t = 0; t < 8; ++t) s[t] = dinv[r[t]];
#pragma unroll
        for (int t = 0; t < 8; ++t) h[t] = H2[(size_t)r[t] * 32 + lane];
#pragma unroll
        for (int t = 0; t < 8; ++t) {
            acc.x += s[t] * bf2f(h[t].x); acc.y += s[t] * bf2f(h[t].y);
            acc.z += s[t] * bf2f(h[t].z); acc.w += s[t] * bf2f(h[t].w);
        }
    }
    for (; j < end; ++j) {
        int r0 = srcs[j];
        float s0 = dinv[r0];
        ushort4 h0 = H2[(size_t)r0 * 32 + lane];
        acc.x += s0 * bf2f(h0.x); acc.y += s0 * bf2f(h0.y);
        acc.z += s0 * bf2f(h0.z); acc.w += s0 * bf2f(h0.w);
    }
    ushort4 o;
    o.x = f2bf(sn * acc.x); o.y = f2bf(sn * acc.y);
    o.z = f2bf(sn * acc.z); o.w = f2bf(sn * acc.w);
    ((ushort4*)Pb)[(size_t)node * 32 + lane] = o;
}

// Hn = bf16( relu( Pb @ W + bias ) ) via 16x16x32 bf16 MFMA.
// Block = 4 waves; wave = 16 rows x 128 cols. All row buffers sized Npad ->
// no row guards. Epilogue: per-wave LDS tile (fp32, pitch 132; same-wave
// ordering, no barrier) -> coalesced ushort4 stores. If writeDots: instead
// accumulate rd[i] = sum relu(..)*Wl[col], shfl-reduce over the 16 col-lanes,
// write dots[] only (layer 4: Hn not written, node_dot eliminated).
// C/D: col=lane&15, row=(lane>>4)*4+reg (verified mapping).
__global__ __launch_bounds__(256) void gemm_mfma(const unsigned short* __restrict__ Pb,
                                                 const unsigned short* __restrict__ Wt,
                                                 const float* __restrict__ bias,
                                                 unsigned short* __restrict__ Hn,
                                                 float* __restrict__ dots,
                                                 const float* __restrict__ Wl,
                                                 int writeDots) {
    __shared__ float tile[4][16 * TP];   // 33.8 KB, one 16x128 tile per wave
    const int wave = threadIdx.x >> 6;
    const int lane = threadIdx.x & 63;
    const int row16 = lane & 15;
    const int quad = lane >> 4;
    const int r0 = blockIdx.x * 64 + wave * 16;
    float* T = tile[wave];

    const bf16x8* Prow = (const bf16x8*)(Pb + (size_t)(r0 + row16) * 128);
    bf16x8 a[4];
#pragma unroll
    for (int kc = 0; kc < 4; ++kc) a[kc] = Prow[kc * 4 + quad];

    float rd[4] = {0.f, 0.f, 0.f, 0.f};
#pragma unroll
    for (int ct = 0; ct < 8; ++ct) {
        const int col = ct * 16 + row16;
        const bf16x8* wc = (const bf16x8*)(Wt + (size_t)col * 128);
        f32x4 acc = {0.f, 0.f, 0.f, 0.f};
#pragma unroll
        for (int kc = 0; kc < 4; ++kc) {
            acc = __builtin_amdgcn_mfma_f32_16x16x32_bf16(a[kc], wc[kc * 4 + quad],
                                                          acc, 0, 0, 0);
        }
        const float bv = bias[col];
        if (writeDots) {
            const float wl = Wl[col];
#pragma unroll
            for (int i = 0; i < 4; ++i) rd[i] += fmaxf(acc[i] + bv, 0.f) * wl;
        } else {
#pragma unroll
            for (int i = 0; i < 4; ++i)
                T[(quad * 4 + i) * TP + col] = fmaxf(acc[i] + bv, 0.f);
        }
    }

    if (writeDots) {
#pragma unroll
        for (int m = 1; m < 16; m <<= 1)
#pragma unroll
            for (int i = 0; i < 4; ++i) rd[i] += __shfl_xor(rd[i], m, 64);
        if (row16 == 0) {
#pragma unroll
            for (int i = 0; i < 4; ++i) dots[r0 + quad * 4 + i] = rd[i];
        }
    } else {
        // coalesced readback: 512 float4 chunks per wave tile, 8 per lane
#pragma unroll
        for (int g = 0; g < 8; ++g) {
            int idx = g * 64 + lane;
            int row = idx >> 5, c4 = idx & 31;
            const float4 v = *(const float4*)(T + row * TP + c4 * 4);
            ushort4 o;
            o.x = f2bf(v.x); o.y = f2bf(v.y); o.z = f2bf(v.z); o.w = f2bf(v.w);
            *(ushort4*)(Hn + (size_t)(r0 + row) * 128 + c4 * 4) = o;
        }
    }
}

// one block per graph: binary-search node range in sorted batch, mean, +bl
__global__ __launch_bounds__(256) void pool_graphs(const float* __restrict__ dots,
                                                   const int* __restrict__ batch, int N,
                                                   const float* __restrict__ bl,
                                                   float* __restrict__ out) {
    __shared__ int bounds[2];
    __shared__ float red[4];
    const int g = blockIdx.x;
    const int t = threadIdx.x;
    if (t < 2) {
        int key = g + t;             // lower_bound(batch, key)
        int lo = 0, hi = N;
        while (lo < hi) {
            int mid = (lo + hi) >> 1;
            if (batch[mid] < key) lo = mid + 1; else hi = mid;
        }
        bounds[t] = lo;
    }
    __syncthreads();
    const int lo = bounds[0], hi = bounds[1];
    float s = 0.f;
    for (int i = lo + t; i < hi; i += 256) s += dots[i];
#pragma unroll
    for (int off = 32; off > 0; off >>= 1) s += __shfl_down(s, off, 64);
    if ((t & 63) == 0) red[t >> 6] = s;
    __syncthreads();
    if (t == 0) {
        float tot = red[0] + red[1] + red[2] + red[3];
        int cnt = hi - lo;
        out[g] = tot / (float)(cnt > 0 ? cnt : 1) + bl[0];
    }
}

extern "C" void kernel_launch(void* const* d_in, const int* in_sizes, int n_in,
                              void* d_out, int out_size, void* d_ws, size_t ws_size,
                              hipStream_t stream) {
    const float* x     = (const float*)d_in[0];
    const int*   eidx  = (const int*)d_in[1];    // int32 (harness converts int64)
    const int*   batch = (const int*)d_in[2];
    const float* Ws    = (const float*)d_in[3];
    const float* bs    = (const float*)d_in[4];
    const float* Wl    = (const float*)d_in[5];
    const float* bl    = (const float*)d_in[6];
    (void)n_in; (void)out_size;

    const int N = in_sizes[0] / D;
    const int E = in_sizes[1] / 2;
    const int* er = eidx;       // sources
    const int* ec = eidx + E;   // targets
    const int NBUCK = (N + 511) >> BSH;          // 512-node buckets (<= 256)
    const int NCHUNK = (E + CHUNK - 1) / CHUNK;

    // ---- workspace carve ----
    const int Npad = (N + 63) & ~63;
    const size_t hBytes = (size_t)Npad * D * sizeof(unsigned short); // 25.6 MB bf16
    auto al = [](size_t v) { return (v + 255) & ~(size_t)255; };
    char* base = (char*)d_ws;
    size_t off = 0;

    unsigned short* Pb = (unsigned short*)base;  off = al(hBytes);
    int2* pairs = (int2*)Pb;                     // aliases Pb (CSR build precedes layers)
    int* bucketCnt  = (int*)(base + off);        // zero-block: bucketCnt + globCursor
    int* globCursor = bucketCnt + 256;
    off = al(off + 512 * sizeof(int));
    int*   bucketBase = (int*)(base + off);  off = al(off + 256 * sizeof(int));
    float* dinv   = (float*)(base + off);    off = al(off + (size_t)Npad * sizeof(float));
    float* dots   = (float*)(base + off);    off = al(off + (size_t)Npad * sizeof(float));
    int*   rowptr = (int*)(base + off);      off = al(off + (size_t)(Npad + 64) * sizeof(int));
    int*   srcs   = (int*)(base + off);      off = al(off + (size_t)E * sizeof(int));
    unsigned short* Wt = (unsigned short*)(base + off);   off = al(off + 4 * 128 * 128 * sizeof(unsigned short));
    unsigned short* Hb0 = (unsigned short*)(base + off);  off = al(off + hBytes);

    // second bf16 buffer: in ws if it fits, else reuse x's 51.2 MB input buffer
    // (Npad*256B <= N*512B for N >= 63, so the alias stays in-bounds)
    const bool twoBuf = ws_size >= off + hBytes;
    unsigned short* Hb1 = twoBuf ? (unsigned short*)(base + off)
                                 : (unsigned short*)d_in[0];
    unsigned short* hb[2] = { Hb0, Hb1 };

    // ---- casts (x first: Hb1 may alias x's buffer) ----
    const int n4 = N * D / 4;
    cast_bf16<<<(n4 + 255) / 256, 256, 0, stream>>>((const float4*)x, (ushort4*)Hb0, n4);
    cast_w<<<256, 256, 0, stream>>>(Ws, Wt);

    // ---- binned CSR build (once; reused by all 4 layers) ----
    zero_i4<<<1, 256, 0, stream>>>((int4*)bucketCnt, 128);
    hist_pass<<<NCHUNK, 256, 0, stream>>>(ec, E, bucketCnt);
    bucket_scan<<<1, 256, 0, stream>>>(bucketCnt, bucketBase, globCursor);
    scatter_pairs<<<NCHUNK, 256, 0, stream>>>(er, ec, E, globCursor, pairs);
    fill_csr<<<NBUCK, 256, 0, stream>>>(pairs, bucketBase, bucketCnt, N, E, NBUCK,
                                        rowptr, dinv, srcs);

    // ---- 4 layers: pull (bf16 gather -> bf16 Pb) -> MFMA gemm ----
    for (int i = 0; i < 4; ++i) {
        const unsigned short* Hc = hb[i & 1];
        unsigned short* Hn = hb[(i + 1) & 1];
        pull_agg<<<(N + 7) / 8, 256, 0, stream>>>(rowptr, srcs, dinv, Hc, Pb, N);
        gemm_mfma<<<Npad / 64, 256, 0, stream>>>(Pb, Wt + (size_t)i * D * D,
                                                 bs + (size_t)i * D, Hn, dots, Wl,
                                                 (i == 3) ? 1 : 0);
    }

    // ---- mean pool (+bl) over fused per-node dots ----
    pool_graphs<<<NGRAPH, 256, 0, stream>>>(dots, batch, N, bl, (float*)d_out);
}

// Round 12
// 523.801 us; speedup vs baseline: 1.9815x; 1.0869x over previous
//
#include <hip/hip_runtime.h>

// ---------------------------------------------------------------------------
// GCN forward, reassociated: per layer h = relu( (A_hat h) W + b ).
// Structure: bf16 features (pull is L3-restream throughput-bound: FETCH =
// 8 XCDs x |H|, at floor), binned no-atomic-hotpath CSR build, pull-side
// aggregation, MFMA GEMM, head-dot fused into layer 4, atomic-free pooling.
// R12: gemm rewritten — R11 evidence says gemm (~30us each) is bound by
// 16-row-strided 16B operand gathers (A-frags from Pb + full 32KB Wt re-
// gathered per wave). Now: wave = 32 rows (W-frag reuse x2), A staged via
// coalesced loads into xor-swizzled LDS (conflict-free ds_read_b128 frags),
// LDS region reused as bf16 out tile for coalesced stores.
// Also: cast_bf16 + cast_w + hist merged into one launch; zero via memset.
// NOTE: harness delivers integer inputs as int32 (edge_index/batch: int*).
// ---------------------------------------------------------------------------

constexpr int D = 128;
constexpr int NGRAPH = 512;
constexpr int CHUNK = 4096;       // edges per scatter block
constexpr int BSH = 9;            // 512 nodes per bucket
constexpr int OP = 136;           // gemm out-tile pitch (ushorts): 272B, 16B-aligned rows

typedef __attribute__((ext_vector_type(8))) short bf16x8;
typedef __attribute__((ext_vector_type(4))) float f32x4;

__device__ __forceinline__ float bf2f(unsigned short b) {
    return __uint_as_float(((unsigned int)b) << 16);
}
__device__ __forceinline__ unsigned short f2bf(float f) {   // round-to-nearest-even
    unsigned int u = __float_as_uint(f);
    u += 0x7FFFu + ((u >> 16) & 1u);
    return (unsigned short)(u >> 16);
}

// merged independent setup: [0,CB) cast x->bf16 | [CB,CB+256) cast W ->
// transposed bf16 Wt | [CB+256, ...) per-chunk bucket histogram.
__global__ __launch_bounds__(256) void setup_all(
        const float4* __restrict__ x4, ushort4* __restrict__ hb, int n4, int CB,
        const float* __restrict__ W, unsigned short* __restrict__ Wt,
        const int* __restrict__ ec, int E, int* __restrict__ bucketCnt) {
    __shared__ int h[256];
    const int t = threadIdx.x;
    const int b = blockIdx.x;
    if (b < CB) {
        int i = b * 256 + t;
        if (i < n4) {
            float4 v = x4[i];
            ushort4 o;
            o.x = f2bf(v.x); o.y = f2bf(v.y); o.z = f2bf(v.z); o.w = f2bf(v.w);
            hb[i] = o;
        }
    } else if (b < CB + 256) {
        int idx = (b - CB) * 256 + t;      // 4*128*128 = 65536 elems
        int i = idx >> 14;
        int rem = idx & 16383;
        int k = rem >> 7, c = rem & 127;
        Wt[(i << 14) + c * 128 + k] = f2bf(W[idx]);
    } else {
        h[t] = 0;
        __syncthreads();
        const int e0 = (b - CB - 256) * CHUNK;
        const int cnt = min(CHUNK, E - e0);
        for (int i = t; i < cnt; i += 256) atomicAdd(&h[ec[e0 + i] >> BSH], 1);
        __syncthreads();
        if (h[t]) atomicAdd(&bucketCnt[t], h[t]);
    }
}

// exclusive scan over 256 bucket counts -> bucketBase, globCursor
__global__ __launch_bounds__(256) void bucket_scan(const int* __restrict__ bucketCnt,
                                                   int* __restrict__ bucketBase,
                                                   int* __restrict__ globCursor) {
    __shared__ int s[256];
    const int t = threadIdx.x;
    int v = bucketCnt[t];
    s[t] = v; __syncthreads();
    for (int off = 1; off < 256; off <<= 1) {
        int x = (t >= off) ? s[t - off] : 0;
        __syncthreads();
        s[t] += x;
        __syncthreads();
    }
    int excl = s[t] - v;
    bucketBase[t] = excl;
    globCursor[t] = excl;
}

// scatter (r,c) pairs into bucket-grouped array, LDS-staged & coalesced
__global__ __launch_bounds__(256) void scatter_pairs(const int* __restrict__ er,
                                                     const int* __restrict__ ec, int E,
                                                     int* __restrict__ globCursor,
                                                     int2* __restrict__ pairs) {
    __shared__ int h[256], lbase[256], cur[256], segd[256], s[256];
    __shared__ int2 stage[CHUNK];
    const int t = threadIdx.x;
    const int e0 = blockIdx.x * CHUNK;
    const int cnt = min(CHUNK, E - e0);

    h[t] = 0;
    __syncthreads();
    for (int i = t; i < cnt; i += 256) atomicAdd(&h[ec[e0 + i] >> BSH], 1);
    __syncthreads();
    int v = h[t];
    s[t] = v; __syncthreads();
    for (int off = 1; off < 256; off <<= 1) {
        int x = (t >= off) ? s[t - off] : 0;
        __syncthreads();
        s[t] += x;
        __syncthreads();
    }
    lbase[t] = s[t] - v;
    cur[t] = s[t] - v;
    segd[t] = atomicAdd(&globCursor[t], v) - lbase[t];
    __syncthreads();
    for (int i = t; i < cnt; i += 256) {
        int c = ec[e0 + i];
        int b = c >> BSH;
        int p = atomicAdd(&cur[b], 1);
        stage[p] = make_int2(er[e0 + i], c);
    }
    __syncthreads();
    for (int i = t; i < cnt; i += 256) {
        int2 pr = stage[i];
        int b = pr.y >> BSH;
        pairs[segd[b] + i] = pr;
    }
}

// one block per bucket. LDS hist+scan -> rowptr, dinv, slot fill.
__global__ __launch_bounds__(256) void fill_csr(const int2* __restrict__ pairs,
                                                const int* __restrict__ bucketBase,
                                                const int* __restrict__ bucketCnt,
                                                int N, int E, int NBUCK,
                                                int* __restrict__ rowptr,
                                                float* __restrict__ dinv,
                                                int* __restrict__ srcs) {
    __shared__ int hist[512], lofs[512], s[256];
    const int t = threadIdx.x;
    const int b = blockIdx.x;
    const int c0 = b << BSH;
    const int base = bucketBase[b];
    const int cnt = bucketCnt[b];
    const int2* pp = pairs + base;

    hist[t] = 0; hist[t + 256] = 0;
    __syncthreads();
    for (int i = t; i < cnt; i += 256) atomicAdd(&hist[pp[i].y - c0], 1);
    __syncthreads();
    int a0 = hist[2 * t], a1 = hist[2 * t + 1];
    s[t] = a0 + a1; __syncthreads();
    for (int off = 1; off < 256; off <<= 1) {
        int x = (t >= off) ? s[t - off] : 0;
        __syncthreads();
        s[t] += x;
        __syncthreads();
    }
    int excl = s[t] - (a0 + a1);
    lofs[2 * t] = excl;
    lofs[2 * t + 1] = excl + a0;
    __syncthreads();
    const int nn = min(512, N - c0);
    for (int i = t; i < nn; i += 256) {
        rowptr[c0 + i] = base + lofs[i];
        dinv[c0 + i] = rsqrtf((float)hist[i] + 1.0f);
    }
    if (b == NBUCK - 1 && t == 0) rowptr[N] = E;
    __syncthreads();
    for (int i = t; i < cnt; i += 256) {
        int2 pr = pp[i];
        int p = atomicAdd(&lofs[pr.y - c0], 1);
        srcs[base + p] = pr.x;
    }
}

// Pb[n][:] = bf16( dinv[n]*( sum_j dinv[srcs[j]]*H[srcs[j]][:] + dinv[n]*H[n][:] ) )
__global__ __launch_bounds__(256) void pull_agg(const int* __restrict__ rowptr,
                                                const int* __restrict__ srcs,
                                                const float* __restrict__ dinv,
                                                const unsigned short* __restrict__ H,
                                                unsigned short* __restrict__ Pb, int N) {
    int node = blockIdx.x * 8 + (threadIdx.x >> 5);
    int lane = threadIdx.x & 31;
    if (node >= N) return;
    int j = rowptr[node], end = rowptr[node + 1];
    const ushort4* H2 = (const ushort4*)H;   // 32 ushort4 per row
    float sn = dinv[node];
    ushort4 hs = H2[(size_t)node * 32 + lane];
    float4 acc = make_float4(sn * bf2f(hs.x), sn * bf2f(hs.y),
                             sn * bf2f(hs.z), sn * bf2f(hs.w));
    for (; j + 8 <= end; j += 8) {
        int r[8]; float s[8]; ushort4 h[8];
#pragma unroll
        for (int t = 0; t < 8; ++t) r[t] = srcs[j + t];
#pragma unroll
        for (int t = 0; t < 8; ++t) s[t] = dinv[r[t]];
#pragma unroll
        for (int t = 0; t < 8; ++t) h[t] = H2[(size_t)r[t] * 32 + lane];
#pragma unroll
        for (int t = 0; t < 8; ++t) {
            acc.x += s[t] * bf2f(h[t].x); acc.y += s[t] * bf2f(h[t].y);
            acc.z += s[t] * bf2f(h[t].z); acc.w += s[t] * bf2f(h[t].w);
        }
    }
    for (; j < end; ++j) {
        int r0 = srcs[j];
        float s0 = dinv[r0];
        ushort4 h0 = H2[(size_t)r0 * 32 + lane];
        acc.x += s0 * bf2f(h0.x); acc.y += s0 * bf2f(h0.y);
        acc.z += s0 * bf2f(h0.z); acc.w += s0 * bf2f(h0.w);
    }
    ushort4 o;
    o.x = f2bf(sn * acc.x); o.y = f2bf(sn * acc.y);
    o.z = f2bf(sn * acc.z); o.w = f2bf(sn * acc.w);
    ((ushort4*)Pb)[(size_t)node * 32 + lane] = o;
}

// Hn = bf16( relu( Pb @ W + bias ) ) via 16x16x32 bf16 MFMA.
// Block = 4 waves; wave = 32 rows (2 row-tiles, W-frag reuse x2).
// Phase 1: coalesced-stage 32 Pb rows into per-wave LDS, 16B chunks xor-
// swizzled by (row&15) -> ds_read_b128 frag loads hit the 8-words/bank
// minimum (conflict-free). Phase 2: A-frags to regs; LDS reused as bf16 out
// tile (pitch OP=136, readback conflict-free) -> coalesced 16B stores.
// Layer 4 (writeDots): head dot fused, no Hn write.
// C/D: col=lane&15, row=(lane>>4)*4+reg (verified mapping).
__global__ __launch_bounds__(256) void gemm_mfma(const unsigned short* __restrict__ Pb,
                                                 const unsigned short* __restrict__ Wt,
                                                 const float* __restrict__ bias,
                                                 unsigned short* __restrict__ Hn,
                                                 float* __restrict__ dots,
                                                 const float* __restrict__ Wl,
                                                 int writeDots) {
    __shared__ __align__(16) unsigned short u[4][32 * OP];   // 34 KB
    const int wave = threadIdx.x >> 6;
    const int lane = threadIdx.x & 63;
    const int row16 = lane & 15;
    const int quad = lane >> 4;
    const int r0 = blockIdx.x * 128 + wave * 32;
    unsigned short* U = u[wave];

    // ---- stage 32 rows (A-layout: pitch 128, xor-swizzled 16B chunks) ----
    {
        const int lr = lane >> 1, hf = lane & 1;   // lane covers 128B of row lr
        const bf16x8* g = (const bf16x8*)(Pb + (size_t)(r0 + lr) * 128);
        bf16x8* l = (bf16x8*)(U + lr * 128);
#pragma unroll
        for (int i = 0; i < 8; ++i) {
            int c = hf * 8 + i;
            l[c ^ (lr & 15)] = g[c];
        }
    }
    __syncthreads();

    // ---- A fragments for both 16-row tiles, all 4 K-chunks ----
    bf16x8 a0[4], a1[4];
#pragma unroll
    for (int kc = 0; kc < 4; ++kc) {
        const int ph = (kc * 4 + quad) ^ row16;
        a0[kc] = *(const bf16x8*)(U + row16 * 128 + ph * 8);
        a1[kc] = *(const bf16x8*)(U + (16 + row16) * 128 + ph * 8);
    }
    __syncthreads();   // U is now reused as the out tile (pitch OP)

    float rd0[4] = {0.f, 0.f, 0.f, 0.f}, rd1[4] = {0.f, 0.f, 0.f, 0.f};
#pragma unroll
    for (int ct = 0; ct < 8; ++ct) {
        const int col = ct * 16 + row16;
        const bf16x8* wc = (const bf16x8*)(Wt + (size_t)col * 128);
        f32x4 acc0 = {0.f, 0.f, 0.f, 0.f}, acc1 = {0.f, 0.f, 0.f, 0.f};
#pragma unroll
        for (int kc = 0; kc < 4; ++kc) {
            const bf16x8 wf = wc[kc * 4 + quad];
            acc0 = __builtin_amdgcn_mfma_f32_16x16x32_bf16(a0[kc], wf, acc0, 0, 0, 0);
            acc1 = __builtin_amdgcn_mfma_f32_16x16x32_bf16(a1[kc], wf, acc1, 0, 0, 0);
        }
        const float bv = bias[col];
        if (writeDots) {
            const float wl = Wl[col];
#pragma unroll
            for (int i = 0; i < 4; ++i) {
                rd0[i] += fmaxf(acc0[i] + bv, 0.f) * wl;
                rd1[i] += fmaxf(acc1[i] + bv, 0.f) * wl;
            }
        } else {
#pragma unroll
            for (int i = 0; i < 4; ++i) {
                U[(quad * 4 + i) * OP + col] = f2bf(fmaxf(acc0[i] + bv, 0.f));
                U[(16 + quad * 4 + i) * OP + col] = f2bf(fmaxf(acc1[i] + bv, 0.f));
            }
        }
    }

    if (writeDots) {
#pragma unroll
        for (int m = 1; m < 16; m <<= 1)
#pragma unroll
            for (int i = 0; i < 4; ++i) {
                rd0[i] += __shfl_xor(rd0[i], m, 64);
                rd1[i] += __shfl_xor(rd1[i], m, 64);
            }
        if (row16 == 0) {
#pragma unroll
            for (int i = 0; i < 4; ++i) {
                dots[r0 + quad * 4 + i] = rd0[i];
                dots[r0 + 16 + quad * 4 + i] = rd1[i];
            }
        }
    } else {
        __syncthreads();
        // coalesced readback + store: 512 16B chunks per wave tile, 8/lane
#pragma unroll
        for (int i = 0; i < 8; ++i) {
            int idx = i * 64 + lane;
            int row = idx >> 4, c8 = idx & 15;
            bf16x8 v = *(const bf16x8*)(U + row * OP + c8 * 8);
            *(bf16x8*)(Hn + (size_t)(r0 + row) * 128 + c8 * 8) = v;
        }
    }
}

// one block per graph: binary-search node range in sorted batch, mean, +bl
__global__ __launch_bounds__(256) void pool_graphs(const float* __restrict__ dots,
                                                   const int* __restrict__ batch, int N,
                                                   const float* __restrict__ bl,
                                                   float* __restrict__ out) {
    __shared__ int bounds[2];
    __shared__ float red[4];
    const int g = blockIdx.x;
    const int t = threadIdx.x;
    if (t < 2) {
        int key = g + t;             // lower_bound(batch, key)
        int lo = 0, hi = N;
        while (lo < hi) {
            int mid = (lo + hi) >> 1;
            if (batch[mid] < key) lo = mid + 1; else hi = mid;
        }
        bounds[t] = lo;
    }
    __syncthreads();
    const int lo = bounds[0], hi = bounds[1];
    float s = 0.f;
    for (int i = lo + t; i < hi; i += 256) s += dots[i];
#pragma unroll
    for (int off = 32; off > 0; off >>= 1) s += __shfl_down(s, off, 64);
    if ((t & 63) == 0) red[t >> 6] = s;
    __syncthreads();
    if (t == 0) {
        float tot = red[0] + red[1] + red[2] + red[3];
        int cnt = hi - lo;
        out[g] = tot / (float)(cnt > 0 ? cnt : 1) + bl[0];
    }
}

extern "C" void kernel_launch(void* const* d_in, const int* in_sizes, int n_in,
                              void* d_out, int out_size, void* d_ws, size_t ws_size,
                              hipStream_t stream) {
    const float* x     = (const float*)d_in[0];
    const int*   eidx  = (const int*)d_in[1];    // int32 (harness converts int64)
    const int*   batch = (const int*)d_in[2];
    const float* Ws    = (const float*)d_in[3];
    const float* bs    = (const float*)d_in[4];
    const float* Wl    = (const float*)d_in[5];
    const float* bl    = (const float*)d_in[6];
    (void)n_in; (void)out_size;

    const int N = in_sizes[0] / D;
    const int E = in_sizes[1] / 2;
    const int* er = eidx;       // sources
    const int* ec = eidx + E;   // targets
    const int NBUCK = (N + 511) >> BSH;          // 512-node buckets (<= 256)
    const int NCHUNK = (E + CHUNK - 1) / CHUNK;

    // ---- workspace carve ----
    const int Npad = (N + 127) & ~127;           // gemm processes 128 rows/block
    const size_t hBytes = (size_t)Npad * D * sizeof(unsigned short); // 25.6 MB bf16
    auto al = [](size_t v) { return (v + 255) & ~(size_t)255; };
    char* base = (char*)d_ws;
    size_t off = 0;

    unsigned short* Pb = (unsigned short*)base;  off = al(hBytes);
    int2* pairs = (int2*)Pb;                     // aliases Pb (CSR build precedes layers)
    int* bucketCnt  = (int*)(base + off);
    int* globCursor = bucketCnt + 256;
    off = al(off + 512 * sizeof(int));
    int*   bucketBase = (int*)(base + off);  off = al(off + 256 * sizeof(int));
    float* dinv   = (float*)(base + off);    off = al(off + (size_t)Npad * sizeof(float));
    float* dots   = (float*)(base + off);    off = al(off + (size_t)Npad * sizeof(float));
    int*   rowptr = (int*)(base + off);      off = al(off + (size_t)(Npad + 64) * sizeof(int));
    int*   srcs   = (int*)(base + off);      off = al(off + (size_t)E * sizeof(int));
    unsigned short* Wt = (unsigned short*)(base + off);   off = al(off + 4 * 128 * 128 * sizeof(unsigned short));
    unsigned short* Hb0 = (unsigned short*)(base + off);  off = al(off + hBytes);

    // second bf16 buffer: in ws if it fits, else reuse x's 51.2 MB input buffer
    // (Npad*256B <= N*512B, so the alias stays in-bounds)
    const bool twoBuf = ws_size >= off + hBytes;
    unsigned short* Hb1 = twoBuf ? (unsigned short*)(base + off)
                                 : (unsigned short*)d_in[0];
    unsigned short* hb[2] = { Hb0, Hb1 };

    // ---- setup: memset bucketCnt; merged cast_x | cast_W | histogram ----
    hipMemsetAsync(bucketCnt, 0, 256 * sizeof(int), stream);
    const int n4 = N * D / 4;
    const int CB = (n4 + 255) / 256;
    setup_all<<<CB + 256 + NCHUNK, 256, 0, stream>>>((const float4*)x, (ushort4*)Hb0,
                                                     n4, CB, Ws, Wt, ec, E, bucketCnt);

    // ---- binned CSR build (once; reused by all 4 layers) ----
    bucket_scan<<<1, 256, 0, stream>>>(bucketCnt, bucketBase, globCursor);
    scatter_pairs<<<NCHUNK, 256, 0, stream>>>(er, ec, E, globCursor, pairs);
    fill_csr<<<NBUCK, 256, 0, stream>>>(pairs, bucketBase, bucketCnt, N, E, NBUCK,
                                        rowptr, dinv, srcs);

    // ---- 4 layers: pull (bf16 gather -> bf16 Pb) -> MFMA gemm ----
    for (int i = 0; i < 4; ++i) {
        const unsigned short* Hc = hb[i & 1];
        unsigned short* Hn = hb[(i + 1) & 1];
        pull_agg<<<(N + 7) / 8, 256, 0, stream>>>(rowptr, srcs, dinv, Hc, Pb, N);
        gemm_mfma<<<Npad / 128, 256, 0, stream>>>(Pb, Wt + (size_t)i * D * D,
                                                  bs + (size_t)i * D, Hn, dots, Wl,
                                                  (i == 3) ? 1 : 0);
    }

    // ---- mean pool (+bl) over fused per-node dots ----
    pool_graphs<<<NGRAPH, 256, 0, stream>>>(dots, batch, N, bl, (float*)d_out);
}